// Round 3
// baseline (248656.128 us; speedup 1.0000x reference)
//
#include <hip/hip_runtime.h>
#include <cstddef>
#include <cstdint>

#define T_INN 200
#define T_OUTT 400
#define BB 64
#define DENC 512
#define NMEL 80
#define NBLK 512

typedef unsigned short u16;
typedef __bf16 bf16x8 __attribute__((ext_vector_type(8)));
typedef float f32x4 __attribute__((ext_vector_type(4)));

__device__ __forceinline__ float sigf(float x) { return 1.0f / (1.0f + expf(-x)); }

__device__ __forceinline__ u16 f2bf(float f) {
  unsigned u = __float_as_uint(f);
  unsigned r = u + 0x7fffu + ((u >> 16) & 1u);
  return (u16)(r >> 16);
}
__device__ __forceinline__ bf16x8 ldbf8(const u16* p) { return *(const bf16x8*)p; }

// ============================ precompute kernels ============================
__global__ __launch_bounds__(256) void gemm_pre_kernel(
    const float* __restrict__ A, int lda, const float* __restrict__ W, int ldw,
    float* __restrict__ C, u16* __restrict__ Cbf, int ldc, int K, int relu)
{
  __shared__ float As[16][66];
  __shared__ float Ws[16][66];
  const int tid = threadIdx.x;
  const int tn = tid & 15, tm = tid >> 4;
  const int n0 = blockIdx.x * 64;
  const int m0 = blockIdx.y * 64;
  float acc[4][4] = {{0.f}};
  for (int kt = 0; kt < K; kt += 16) {
#pragma unroll
    for (int i = 0; i < 4; i++) {
      int e = tid + 256 * i;
      int m = e >> 4, kk = e & 15;
      As[kk][m] = A[(size_t)(m0 + m) * lda + kt + kk];
    }
#pragma unroll
    for (int i = 0; i < 4; i++) {
      int e = tid + 256 * i;
      int n = e >> 4, kk = e & 15;
      Ws[kk][n] = W[(size_t)(n0 + n) * ldw + kt + kk];
    }
    __syncthreads();
#pragma unroll
    for (int kk = 0; kk < 16; kk++) {
      float2 a01 = *(const float2*)&As[kk][tm * 4];
      float2 a23 = *(const float2*)&As[kk][tm * 4 + 2];
      float2 w01 = *(const float2*)&Ws[kk][tn * 4];
      float2 w23 = *(const float2*)&Ws[kk][tn * 4 + 2];
      float a[4] = {a01.x, a01.y, a23.x, a23.y};
      float w[4] = {w01.x, w01.y, w23.x, w23.y};
#pragma unroll
      for (int mi = 0; mi < 4; mi++)
#pragma unroll
        for (int ni = 0; ni < 4; ni++)
          acc[mi][ni] = fmaf(a[mi], w[ni], acc[mi][ni]);
    }
    __syncthreads();
  }
#pragma unroll
  for (int mi = 0; mi < 4; mi++) {
    int m = m0 + tm * 4 + mi;
    float v0 = acc[mi][0], v1 = acc[mi][1], v2 = acc[mi][2], v3 = acc[mi][3];
    if (relu) {
      v0 = fmaxf(v0, 0.f); v1 = fmaxf(v1, 0.f);
      v2 = fmaxf(v2, 0.f); v3 = fmaxf(v3, 0.f);
    }
    if (Cbf) {
      u16* p = Cbf + (size_t)m * ldc + n0 + tn * 4;
      p[0] = f2bf(v0); p[1] = f2bf(v1); p[2] = f2bf(v2); p[3] = f2bf(v3);
    } else {
      float4 vv; vv.x = v0; vv.y = v1; vv.z = v2; vv.w = v3;
      *(float4*)&C[(size_t)m * ldc + n0 + tn * 4] = vv;
    }
  }
}

__global__ __launch_bounds__(256) void pack_w_kernel(
    const float* __restrict__ W, u16* __restrict__ P,
    int K, int KTl, int ktOff, int KTtot, int total)
{
  int slot = blockIdx.x * 256 + threadIdx.x;
  if (slot >= total) return;
  int lane = slot & 63;
  int ktl = (slot >> 6) % KTl;
  int nt = slot / (64 * KTl);
  int n = nt * 16 + (lane & 15);
  int k = ktl * 32 + (lane >> 4) * 8;
  const float* src = W + (size_t)n * K + k;
  u16 tmp[8];
#pragma unroll
  for (int i = 0; i < 8; i++) tmp[i] = f2bf(src[i]);
  u16* dst = P + ((size_t)(nt * KTtot + (ktl + ktOff)) * 64 + lane) * 8;
  *(uint4*)dst = *(const uint4*)tmp;
}

__global__ void transpose_pm_kernel(const float* __restrict__ pm, float* __restrict__ pmT)
{
  int b = blockIdx.z;
  int tT = blockIdx.x * 32, aT = blockIdx.y * 32;
  __shared__ float tile[32][33];
  int tx = threadIdx.x, ty = threadIdx.y;
#pragma unroll
  for (int i = 0; i < 4; i++) {
    int t = tT + ty + i * 8;
    int a = aT + tx;
    if (t < T_INN) tile[ty + i * 8][tx] = pm[((size_t)b * T_INN + t) * 128 + a];
  }
  __syncthreads();
#pragma unroll
  for (int i = 0; i < 4; i++) {
    int a = aT + ty + i * 8;
    int t = tT + tx;
    if (t < T_INN) pmT[((size_t)b * 128 + a) * T_INN + t] = tile[tx][ty + i * 8];
  }
}

// ============================ persistent decoder ============================
// grid = 512 blocks x 256 threads = 2 blocks/CU on 256 CUs (co-resident:
// LDS ~9.5KB/block, __launch_bounds__(256,2) caps VGPR; 8 waves/CU).

struct __align__(16) Smem {
  union {
    struct { float aS[T_INN]; float cS[T_INN]; float wc[1984]; } conv;
    struct { float pp[32][9]; float wl[32][33]; float pq[32]; float vS[32]; } en;
    struct { float red[256]; float awS[256]; float cp[256]; } sc;
    struct { float red[256]; } op;
  } u;
};

// two-level grid barrier, agent scope (device-coherent across XCDs)
__device__ __forceinline__ void gbar(unsigned* bar, unsigned k)
{
  __syncthreads();
  if (threadIdx.x == 0) {
    unsigned* gen  = bar;
    unsigned* mcnt = bar + 16;
    unsigned* gcnt = bar + 32 + (blockIdx.x >> 6) * 16;
    unsigned a = __hip_atomic_fetch_add(gcnt, 1u, __ATOMIC_ACQ_REL, __HIP_MEMORY_SCOPE_AGENT);
    if (a == 63u) {
      __hip_atomic_store(gcnt, 0u, __ATOMIC_RELAXED, __HIP_MEMORY_SCOPE_AGENT);
      unsigned m = __hip_atomic_fetch_add(mcnt, 1u, __ATOMIC_ACQ_REL, __HIP_MEMORY_SCOPE_AGENT);
      if (m == 7u) {
        __hip_atomic_store(mcnt, 0u, __ATOMIC_RELAXED, __HIP_MEMORY_SCOPE_AGENT);
        __hip_atomic_store(gen, k, __ATOMIC_RELEASE, __HIP_MEMORY_SCOPE_AGENT);
      } else {
        while (__hip_atomic_load(gen, __ATOMIC_ACQUIRE, __HIP_MEMORY_SCOPE_AGENT) < k)
          __builtin_amdgcn_s_sleep(1);
      }
    } else {
      while (__hip_atomic_load(gen, __ATOMIC_ACQUIRE, __HIP_MEMORY_SCOPE_AGENT) < k)
        __builtin_amdgcn_s_sleep(1);
    }
  }
  __syncthreads();
}

__device__ __forceinline__ void gates_phase(
    const u16* A0, int lda0, int k0,
    const u16* A1, int lda1, int k1,
    const u16* A2, int lda2,
    const u16* __restrict__ Wpack, int KT, int nkt,
    float* __restrict__ Cpart, int bid)
{
  const int tid = threadIdx.x;
  const int w = tid >> 6, lane = tid & 63;
  const int ksplit = bid >> 6;
  const int ngrp = bid & 63;
  const int ntile = ngrp * 4 + w;
  const int kt0 = ksplit * nkt;
  const int mrow = lane & 15;
  const int ksub = (lane >> 4) * 8;
  const int b01 = k0, b12 = k0 + k1;
  f32x4 acc0 = {0.f, 0.f, 0.f, 0.f};
  f32x4 acc1 = acc0, acc2 = acc0, acc3 = acc0;
  for (int kt = kt0; kt < kt0 + nkt; kt++) {
    int kb = kt * 32;
    const u16* Ap; int lda;
    if (kb < b01)      { Ap = A0; lda = lda0; }
    else if (kb < b12) { Ap = A1; lda = lda1; kb -= b01; }
    else               { Ap = A2; lda = lda2; kb -= b12; }
    const u16* abase = Ap + (size_t)mrow * lda + kb + ksub;
    bf16x8 bv = ldbf8(Wpack + ((size_t)(ntile * KT + kt) * 64 + lane) * 8);
    bf16x8 a0 = ldbf8(abase);
    bf16x8 a1 = ldbf8(abase + 16 * lda);
    bf16x8 a2 = ldbf8(abase + 32 * lda);
    bf16x8 a3 = ldbf8(abase + 48 * lda);
    acc0 = __builtin_amdgcn_mfma_f32_16x16x32_bf16(a0, bv, acc0, 0, 0, 0);
    acc1 = __builtin_amdgcn_mfma_f32_16x16x32_bf16(a1, bv, acc1, 0, 0, 0);
    acc2 = __builtin_amdgcn_mfma_f32_16x16x32_bf16(a2, bv, acc2, 0, 0, 0);
    acc3 = __builtin_amdgcn_mfma_f32_16x16x32_bf16(a3, bv, acc3, 0, 0, 0);
  }
  float* C = Cpart + (size_t)ksplit * (64 * 4096);
  const int n = ntile * 16 + (lane & 15);
  const int rb = (lane >> 4) * 4;
#pragma unroll
  for (int r = 0; r < 4; r++) {
    C[(size_t)(0 + rb + r) * 4096 + n]  = acc0[r];
    C[(size_t)(16 + rb + r) * 4096 + n] = acc1[r];
    C[(size_t)(32 + rb + r) * 4096 + n] = acc2[r];
    C[(size_t)(48 + rb + r) * 4096 + n] = acc3[r];
  }
}

__global__ __launch_bounds__(256, 2) void decoder_persist(
    const float* __restrict__ enc, const int* __restrict__ lens,
    const u16* __restrict__ xs_bf, const float* __restrict__ pmT,
    const u16* __restrict__ Wa_pack, const u16* __restrict__ Wd_pack,
    const float* __restrict__ b_a, const float* __restrict__ b_d,
    const float* __restrict__ Wq, const float* __restrict__ Wconv,
    const float* __restrict__ Wloc, const float* __restrict__ vvec,
    const float* __restrict__ Wp, const float* __restrict__ bp,
    float* __restrict__ ah, float* __restrict__ ac,
    float* __restrict__ dh, float* __restrict__ dc,
    float* __restrict__ actx, float* __restrict__ aw, float* __restrict__ awcum,
    u16* __restrict__ ah_bf, u16* __restrict__ dh_bf, u16* __restrict__ actx_bf,
    float* __restrict__ ga, float* __restrict__ gd,
    float* __restrict__ convG, float* __restrict__ epG,
    unsigned* __restrict__ bar,
    float* __restrict__ outsOut, float* __restrict__ alignsOut)
{
  __shared__ Smem sm;
  const int bid = blockIdx.x;
  const int tid = threadIdx.x;
  unsigned k = 0;

  for (int t = 0; t <= T_OUTT; t++) {
    // ---- Phase A: gatesA(t) [448 blk] + lstm_actD(t-1) [64 blk] ----
    if (t < T_OUTT && bid < 448) {
      gates_phase(xs_bf + (size_t)t * 64 * 256, 256, 256,
                  actx_bf, 512, 512, ah_bf, 1024,
                  Wa_pack, 56, 8, ga, bid);
    } else if (bid >= 448 && t > 0) {
      int b2 = bid - 448;
      int j = tid * 4;
      float4 gi = {0,0,0,0}, gf = gi, gg = gi, go = gi;
#pragma unroll
      for (int s = 0; s < 8; s++) {
        const float* g = gd + (size_t)s * (64 * 4096) + (size_t)b2 * 4096 + j;
        float4 v;
        v = *(const float4*)(g);        gi.x+=v.x; gi.y+=v.y; gi.z+=v.z; gi.w+=v.w;
        v = *(const float4*)(g + 1024); gf.x+=v.x; gf.y+=v.y; gf.z+=v.z; gf.w+=v.w;
        v = *(const float4*)(g + 2048); gg.x+=v.x; gg.y+=v.y; gg.z+=v.z; gg.w+=v.w;
        v = *(const float4*)(g + 3072); go.x+=v.x; go.y+=v.y; go.z+=v.z; go.w+=v.w;
      }
      float4 bi = *(const float4*)(b_d + j);
      float4 bf = *(const float4*)(b_d + 1024 + j);
      float4 bg = *(const float4*)(b_d + 2048 + j);
      float4 bo = *(const float4*)(b_d + 3072 + j);
      int idx = b2 * 1024 + j;
#pragma unroll
      for (int q = 0; q < 4; q++) {
        float i_ = ((const float*)&gi)[q] + ((const float*)&bi)[q];
        float f_ = ((const float*)&gf)[q] + ((const float*)&bf)[q];
        float g_ = ((const float*)&gg)[q] + ((const float*)&bg)[q];
        float o_ = ((const float*)&go)[q] + ((const float*)&bo)[q];
        float cn = sigf(f_) * dc[idx + q] + sigf(i_) * tanhf(g_);
        dc[idx + q] = cn;
        float hn = sigf(o_) * tanhf(cn);
        dh[idx + q] = hn;
        dh_bf[idx + q] = f2bf(hn);
      }
    }
    k++; gbar(bar, k);

    // ---- Phase B: lstm_actA(t)[256] + conv(t)[64] + outproj(t-1)[80] ----
    if (t < T_OUTT && bid < 256) {
      int idx = bid * 256 + tid;
      int b = idx >> 10, j = idx & 1023;
      const float* g0 = ga + (size_t)b * 4096;
      float gi = b_a[j], gf = b_a[j + 1024], gg = b_a[j + 2048], go = b_a[j + 3072];
#pragma unroll
      for (int s = 0; s < 7; s++) {
        const float* g = g0 + (size_t)s * (64 * 4096);
        gi += g[j]; gf += g[j + 1024]; gg += g[j + 2048]; go += g[j + 3072];
      }
      float cn = sigf(gf) * ac[idx] + sigf(gi) * tanhf(gg);
      ac[idx] = cn;
      float hn = sigf(go) * tanhf(cn);
      ah[idx] = hn;
      ah_bf[idx] = f2bf(hn);
    } else if (t < T_OUTT && bid >= 256 && bid < 320) {
      int b = bid - 256;
      if (tid < T_INN) {
        sm.u.conv.aS[tid] = aw[b * T_INN + tid];
        sm.u.conv.cS[tid] = awcum[b * T_INN + tid];
      }
      for (int i = tid; i < 1984; i += 256) sm.u.conv.wc[i] = Wconv[i];
      __syncthreads();
      if (tid < T_INN) {
        float acc[32];
#pragma unroll
        for (int f = 0; f < 32; f++) acc[f] = 0.f;
        for (int kk = 0; kk < 31; kk++) {
          int tt = tid + kk - 15;
          if (tt >= 0 && tt < T_INN) {
            float a = sm.u.conv.aS[tt], c = sm.u.conv.cS[tt];
#pragma unroll
            for (int f = 0; f < 32; f++)
              acc[f] += sm.u.conv.wc[f * 62 + kk] * a + sm.u.conv.wc[f * 62 + 31 + kk] * c;
          }
        }
        float4* dst = (float4*)(convG + ((size_t)b * T_INN + tid) * 32);
#pragma unroll
        for (int i = 0; i < 8; i++) {
          float4 v; v.x = acc[i*4]; v.y = acc[i*4+1]; v.z = acc[i*4+2]; v.w = acc[i*4+3];
          dst[i] = v;
        }
      }
    }
    if (t > 0 && bid >= 320 && bid < 400) {
      int ob = bid - 320;
      int oi = tid >> 2, kq = tid & 3;
      int o = ob * 64 + oi;
      int b = o / NMEL, m = o - b * NMEL;
      int tt = t - 1;
      int k4 = kq * 96, k4end = k4 + 96;
      float s = 0.f;
      const float4* wp4 = (const float4*)(Wp + (size_t)m * 1536);
      const float4* dh4 = (const float4*)(dh + (size_t)b * 1024);
      const float4* cx4 = (const float4*)(actx + (size_t)b * 512);
      int kaend = k4end < 256 ? k4end : 256;
#pragma unroll 4
      for (int i = k4; i < kaend; i++) {
        float4 w = wp4[i], a = dh4[i];
        s += w.x * a.x + w.y * a.y + w.z * a.z + w.w * a.w;
      }
      int kbst = k4 > 256 ? k4 : 256;
#pragma unroll 4
      for (int i = kbst; i < k4end; i++) {
        float4 w = wp4[i], a = cx4[i - 256];
        s += w.x * a.x + w.y * a.y + w.z * a.z + w.w * a.w;
      }
      sm.u.op.red[tid] = s;
      __syncthreads();
      if (kq == 0) {
        float tot = sm.u.op.red[tid] + sm.u.op.red[tid + 1] + sm.u.op.red[tid + 2] +
                    sm.u.op.red[tid + 3] + bp[m];
        outsOut[((size_t)b * T_OUTT + tt) * NMEL + m] = tot;
      }
    }
    k++; gbar(bar, k);
    if (t == T_OUTT) break;

    // ---- Phase C: energies + pq [256 blk = (b, a-group)] ----
    if (bid < 256) {
      int b = bid >> 2, g = bid & 3;
      for (int i = tid; i < 1024; i += 256) {
        int ai = i >> 5, f = i & 31;
        sm.u.en.wl[ai][f] = Wloc[(g * 32 + ai) * 32 + f];
      }
      {
        int ai = tid >> 3, kq = tid & 7;
        const float4* hv = (const float4*)(ah + (size_t)b * 1024 + kq * 128);
        const float4* wv = (const float4*)(Wq + (size_t)(g * 32 + ai) * 1024 + kq * 128);
        float s = 0.f;
#pragma unroll 8
        for (int i = 0; i < 32; i++) {
          float4 w = wv[i], h = hv[i];
          s += w.x * h.x + w.y * h.y + w.z * h.z + w.w * h.w;
        }
        sm.u.en.pp[ai][kq] = s;
      }
      if (tid < 32) sm.u.en.vS[tid] = vvec[g * 32 + tid];
      __syncthreads();
      if (tid < 32) {
        float s = 0.f;
#pragma unroll
        for (int kq = 0; kq < 8; kq++) s += sm.u.en.pp[tid][kq];
        sm.u.en.pq[tid] = s;
      }
      __syncthreads();
      if (tid < T_INN) {
        float cv[32];
        const float4* cg4 = (const float4*)(convG + ((size_t)b * T_INN + tid) * 32);
#pragma unroll
        for (int i = 0; i < 8; i++) {
          float4 v = cg4[i];
          cv[i*4] = v.x; cv[i*4+1] = v.y; cv[i*4+2] = v.z; cv[i*4+3] = v.w;
        }
        const float* pm = pmT + ((size_t)b * 128 + g * 32) * T_INN + tid;
        float e = 0.f;
#pragma unroll 2
        for (int aa = 0; aa < 32; aa++) {
          float x = sm.u.en.pq[aa] + pm[(size_t)aa * T_INN];
#pragma unroll
          for (int f = 0; f < 32; f++) x += sm.u.en.wl[aa][f] * cv[f];
          e += sm.u.en.vS[aa] * tanhf(x);
        }
        epG[(size_t)(b * 4 + g) * T_INN + tid] = e;
      }
    }
    k++; gbar(bar, k);

    // ---- Phase D: softmax + context [256 blk = (b, quarter)] ----
    if (bid < 256) {
      int b = bid >> 2, q = bid & 3;
      float e = -3.0e38f;
      if (tid < T_INN) {
        e = epG[(size_t)(b * 4 + 0) * T_INN + tid] + epG[(size_t)(b * 4 + 1) * T_INN + tid] +
            epG[(size_t)(b * 4 + 2) * T_INN + tid] + epG[(size_t)(b * 4 + 3) * T_INN + tid];
        if (tid >= lens[b]) e = -100000000.0f;
      }
      sm.u.sc.red[tid] = e;
      __syncthreads();
      for (int s2 = 128; s2 > 0; s2 >>= 1) {
        if (tid < s2) sm.u.sc.red[tid] = fmaxf(sm.u.sc.red[tid], sm.u.sc.red[tid + s2]);
        __syncthreads();
      }
      float mx = sm.u.sc.red[0];
      __syncthreads();
      float ex = (tid < T_INN) ? expf(e - mx) : 0.f;
      sm.u.sc.red[tid] = ex;
      __syncthreads();
      for (int s2 = 128; s2 > 0; s2 >>= 1) {
        if (tid < s2) sm.u.sc.red[tid] += sm.u.sc.red[tid + s2];
        __syncthreads();
      }
      float inv = 1.0f / sm.u.sc.red[0];
      float aval = ex * inv;
      sm.u.sc.awS[tid] = (tid < T_INN) ? aval : 0.f;
      if (q == 0 && tid < T_INN) {
        aw[b * T_INN + tid] = aval;
        awcum[b * T_INN + tid] += aval;
        alignsOut[((size_t)b * T_OUTT + t) * T_INN + tid] = aval;
      }
      __syncthreads();
      {
        int d = tid & 127, hh = tid >> 7;
        int e0 = q * 128 + d;
        const float* ep2 = enc + ((size_t)b * T_INN + hh * 100) * DENC + e0;
        float s = 0.f;
#pragma unroll 4
        for (int ttt = 0; ttt < 100; ttt++) s += sm.u.sc.awS[hh * 100 + ttt] * ep2[(size_t)ttt * DENC];
        sm.u.sc.cp[tid] = s;
      }
      __syncthreads();
      if (tid < 128) {
        int e0 = q * 128 + tid;
        float v = sm.u.sc.cp[tid] + sm.u.sc.cp[tid + 128];
        actx[b * DENC + e0] = v;
        actx_bf[b * DENC + e0] = f2bf(v);
      }
    }
    k++; gbar(bar, k);

    // ---- Phase E: gatesD(t) [512 blk] ----
    gates_phase(ah_bf, 1024, 1024, actx_bf, 512, 512, dh_bf, 1024,
                Wd_pack, 80, 10, gd, bid);
    k++; gbar(bar, k);
  }
}

// ============================ launcher ============================
extern "C" void kernel_launch(void* const* d_in, const int* in_sizes, int n_in,
                              void* d_out, int out_size, void* d_ws, size_t ws_size,
                              hipStream_t stream)
{
  const float* enc    = (const float*)d_in[0];
  const float* dec    = (const float*)d_in[1];
  const int*   lens   = (const int*)d_in[2];
  const float* W_p1   = (const float*)d_in[3];
  const float* W_p2   = (const float*)d_in[4];
  const float* W_ih_a = (const float*)d_in[5];
  const float* W_hh_a = (const float*)d_in[6];
  const float* b_a    = (const float*)d_in[7];
  const float* Wq     = (const float*)d_in[8];
  const float* Wmem   = (const float*)d_in[9];
  const float* vvec   = (const float*)d_in[10];
  const float* Wconv  = (const float*)d_in[11];
  const float* Wloc   = (const float*)d_in[12];
  const float* W_ih_d = (const float*)d_in[13];
  const float* W_hh_d = (const float*)d_in[14];
  const float* b_d    = (const float*)d_in[15];
  const float* Wp     = (const float*)d_in[16];
  const float* bp     = (const float*)d_in[17];

  float* ws = (float*)d_ws;
  size_t off = 0;
  u16* xs_bf = (u16*)(ws + off); off += (size_t)T_OUTT * 64 * 256 / 2;
  float* pmT = ws + off; off += (size_t)64 * 128 * T_INN;
  u16* Wa_pack = (u16*)(ws + off); off += (size_t)4096 * 1792 / 2;
  u16* Wd_pack = (u16*)(ws + off); off += (size_t)4096 * 2560 / 2;
  // state block (memset to zero every launch)
  float* stateBase = ws + off;
  float* ah    = stateBase;
  float* ac    = ah + 65536;
  float* dh    = ac + 65536;
  float* dc    = dh + 65536;
  float* actx  = dc + 65536;                    // 64*512
  float* aw    = actx + 32768;                  // 64*200
  float* awcum = aw + 12800;
  u16* ah_bf   = (u16*)(awcum + 12800);         // 65536 u16
  u16* dh_bf   = ah_bf + 65536;
  u16* actx_bf = dh_bf + 65536;                 // 32768 u16
  unsigned* bar = (unsigned*)(actx_bf + 32768); // 256 u32 barrier state
  size_t stateFloats = 4 * 65536 + 32768 + 2 * 12800 + (65536 + 65536 + 32768) / 2 + 256;
  off += stateFloats;
  float* convG = ws + off; off += (size_t)64 * T_INN * 32;   // 409600
  float* epG   = ws + off; off += (size_t)64 * 4 * T_INN;    // 51200
  float* scratch = ws + off;   // max(h1 6.54M, ga 1.84M + gd 2.10M)
  float* h1  = scratch;
  float* pmt = scratch;
  float* ga  = scratch;
  float* gd  = scratch + (size_t)7 * 64 * 4096;

  float* outsOut   = (float*)d_out;
  float* alignsOut = outsOut + (size_t)BB * T_OUTT * NMEL;

  hipMemsetAsync(stateBase, 0, stateFloats * sizeof(float), stream);
  hipMemsetAsync(xs_bf, 0, (size_t)64 * 256 * sizeof(u16), stream);

  // ---- precompute ----
  {
    int tot;
    tot = 256 * 24 * 64;
    pack_w_kernel<<<(tot + 255) / 256, 256, 0, stream>>>(W_ih_a, Wa_pack, 768, 24, 0, 56, tot);
    tot = 256 * 32 * 64;
    pack_w_kernel<<<(tot + 255) / 256, 256, 0, stream>>>(W_hh_a, Wa_pack, 1024, 32, 24, 56, tot);
    tot = 256 * 48 * 64;
    pack_w_kernel<<<(tot + 255) / 256, 256, 0, stream>>>(W_ih_d, Wd_pack, 1536, 48, 0, 80, tot);
    tot = 256 * 32 * 64;
    pack_w_kernel<<<(tot + 255) / 256, 256, 0, stream>>>(W_hh_d, Wd_pack, 1024, 32, 48, 80, tot);
  }
  gemm_pre_kernel<<<dim3(4, 399), 256, 0, stream>>>(dec, 80, W_p1, 80, h1, nullptr, 256, 80, 1);
  gemm_pre_kernel<<<dim3(4, 399), 256, 0, stream>>>(h1, 256, W_p2, 256, nullptr, xs_bf + 64 * 256, 256, 256, 1);
  gemm_pre_kernel<<<dim3(2, 200), 256, 0, stream>>>(enc, 512, Wmem, 512, pmt, nullptr, 128, 512, 0);
  transpose_pm_kernel<<<dim3(7, 4, 64), dim3(32, 8), 0, stream>>>(pmt, pmT);

  // ---- persistent decode loop (single launch, 2002 grid barriers) ----
  decoder_persist<<<NBLK, 256, 0, stream>>>(
      enc, lens, xs_bf, pmT, Wa_pack, Wd_pack, b_a, b_d,
      Wq, Wconv, Wloc, vvec, Wp, bp,
      ah, ac, dh, dc, actx, aw, awcum, ah_bf, dh_bf, actx_bf,
      ga, gd, convG, epG, bar, outsOut, alignsOut);
}

// Round 4
// 103981.128 us; speedup vs baseline: 2.3914x; 2.3914x over previous
//
#include <hip/hip_runtime.h>
#include <cstddef>
#include <cstdint>

#define T_INN 200
#define T_OUTT 400
#define BB 64
#define DENC 512
#define NMEL 80
#define NBLK 512

typedef unsigned short u16;
typedef __bf16 bf16x8 __attribute__((ext_vector_type(8)));
typedef float f32x4 __attribute__((ext_vector_type(4)));

__device__ __forceinline__ float sigf(float x) { return 1.0f / (1.0f + expf(-x)); }

__device__ __forceinline__ u16 f2bf(float f) {
  unsigned u = __float_as_uint(f);
  unsigned r = u + 0x7fffu + ((u >> 16) & 1u);
  return (u16)(r >> 16);
}
__device__ __forceinline__ bf16x8 ldbf8(const u16* p) { return *(const bf16x8*)p; }

// ============================ precompute kernels ============================
__global__ __launch_bounds__(256) void gemm_pre_kernel(
    const float* __restrict__ A, int lda, const float* __restrict__ W, int ldw,
    float* __restrict__ C, u16* __restrict__ Cbf, int ldc, int K, int relu)
{
  __shared__ float As[16][66];
  __shared__ float Ws[16][66];
  const int tid = threadIdx.x;
  const int tn = tid & 15, tm = tid >> 4;
  const int n0 = blockIdx.x * 64;
  const int m0 = blockIdx.y * 64;
  float acc[4][4] = {{0.f}};
  for (int kt = 0; kt < K; kt += 16) {
#pragma unroll
    for (int i = 0; i < 4; i++) {
      int e = tid + 256 * i;
      int m = e >> 4, kk = e & 15;
      As[kk][m] = A[(size_t)(m0 + m) * lda + kt + kk];
    }
#pragma unroll
    for (int i = 0; i < 4; i++) {
      int e = tid + 256 * i;
      int n = e >> 4, kk = e & 15;
      Ws[kk][n] = W[(size_t)(n0 + n) * ldw + kt + kk];
    }
    __syncthreads();
#pragma unroll
    for (int kk = 0; kk < 16; kk++) {
      float2 a01 = *(const float2*)&As[kk][tm * 4];
      float2 a23 = *(const float2*)&As[kk][tm * 4 + 2];
      float2 w01 = *(const float2*)&Ws[kk][tn * 4];
      float2 w23 = *(const float2*)&Ws[kk][tn * 4 + 2];
      float a[4] = {a01.x, a01.y, a23.x, a23.y};
      float w[4] = {w01.x, w01.y, w23.x, w23.y};
#pragma unroll
      for (int mi = 0; mi < 4; mi++)
#pragma unroll
        for (int ni = 0; ni < 4; ni++)
          acc[mi][ni] = fmaf(a[mi], w[ni], acc[mi][ni]);
    }
    __syncthreads();
  }
#pragma unroll
  for (int mi = 0; mi < 4; mi++) {
    int m = m0 + tm * 4 + mi;
    float v0 = acc[mi][0], v1 = acc[mi][1], v2 = acc[mi][2], v3 = acc[mi][3];
    if (relu) {
      v0 = fmaxf(v0, 0.f); v1 = fmaxf(v1, 0.f);
      v2 = fmaxf(v2, 0.f); v3 = fmaxf(v3, 0.f);
    }
    if (Cbf) {
      u16* p = Cbf + (size_t)m * ldc + n0 + tn * 4;
      p[0] = f2bf(v0); p[1] = f2bf(v1); p[2] = f2bf(v2); p[3] = f2bf(v3);
    } else {
      float4 vv; vv.x = v0; vv.y = v1; vv.z = v2; vv.w = v3;
      *(float4*)&C[(size_t)m * ldc + n0 + tn * 4] = vv;
    }
  }
}

__global__ __launch_bounds__(256) void pack_w_kernel(
    const float* __restrict__ W, u16* __restrict__ P,
    int K, int KTl, int ktOff, int KTtot, int total)
{
  int slot = blockIdx.x * 256 + threadIdx.x;
  if (slot >= total) return;
  int lane = slot & 63;
  int ktl = (slot >> 6) % KTl;
  int nt = slot / (64 * KTl);
  int n = nt * 16 + (lane & 15);
  int k = ktl * 32 + (lane >> 4) * 8;
  const float* src = W + (size_t)n * K + k;
  u16 tmp[8];
#pragma unroll
  for (int i = 0; i < 8; i++) tmp[i] = f2bf(src[i]);
  u16* dst = P + ((size_t)(nt * KTtot + (ktl + ktOff)) * 64 + lane) * 8;
  *(uint4*)dst = *(const uint4*)tmp;
}

__global__ void transpose_pm_kernel(const float* __restrict__ pm, float* __restrict__ pmT)
{
  int b = blockIdx.z;
  int tT = blockIdx.x * 32, aT = blockIdx.y * 32;
  __shared__ float tile[32][33];
  int tx = threadIdx.x, ty = threadIdx.y;
#pragma unroll
  for (int i = 0; i < 4; i++) {
    int t = tT + ty + i * 8;
    int a = aT + tx;
    if (t < T_INN) tile[ty + i * 8][tx] = pm[((size_t)b * T_INN + t) * 128 + a];
  }
  __syncthreads();
#pragma unroll
  for (int i = 0; i < 4; i++) {
    int a = aT + ty + i * 8;
    int t = tT + tx;
    if (t < T_INN) pmT[((size_t)b * 128 + a) * T_INN + t] = tile[tx][ty + i * 8];
  }
}

// ============================ persistent decoder ============================
// 512 blocks x 256 threads = 2 blocks/CU co-resident (LDS 9.5KB, VGPR<=256
// via __launch_bounds__(256,2): 8 waves/CU needed, 2048/8=256 VGPR cap).

struct __align__(16) Smem {
  union {
    struct { float aS[T_INN]; float cS[T_INN]; float wc[1984]; } conv;
    struct { float ahS[1024]; float pp[256]; float pq[128]; float red[256]; float awS[256]; } at;
    struct { float red[256]; } op;
  } u;
};

// Grid barrier: RELAXED polls (no per-iteration cache invalidate!) + one
// acquire fence on exit; release fence before arrival. Monotonic generation
// counter (no reset race). Hierarchical gen broadcast: master -> 8 group
// lines -> members, so <=63 blocks poll any single cacheline.
__device__ __forceinline__ void gbar(unsigned* bar, unsigned k)
{
  __syncthreads();
  if (threadIdx.x == 0) {
    unsigned* gen  = bar;                     // line 0
    unsigned* cnt  = bar + 32;                // line 1
    unsigned* ggen = bar + 64;                // lines 2..9 (one per 64-block group)
    const int grp = blockIdx.x >> 6;
    __builtin_amdgcn_fence(__ATOMIC_RELEASE, "agent");   // publish our writes
    unsigned a = __hip_atomic_fetch_add(cnt, 1u, __ATOMIC_RELAXED, __HIP_MEMORY_SCOPE_AGENT);
    bool master = (a == k * NBLK - 1u);
    if (master)
      __hip_atomic_store(gen, k, __ATOMIC_RELAXED, __HIP_MEMORY_SCOPE_AGENT);
    if (master || (blockIdx.x & 63) == 0) {
      while (__hip_atomic_load(gen, __ATOMIC_RELAXED, __HIP_MEMORY_SCOPE_AGENT) < k)
        __builtin_amdgcn_s_sleep(2);
      __hip_atomic_store(ggen + grp * 32, k, __ATOMIC_RELAXED, __HIP_MEMORY_SCOPE_AGENT);
    } else {
      while (__hip_atomic_load(ggen + grp * 32, __ATOMIC_RELAXED, __HIP_MEMORY_SCOPE_AGENT) < k)
        __builtin_amdgcn_s_sleep(2);
    }
    __builtin_amdgcn_fence(__ATOMIC_ACQUIRE, "agent");   // make others' writes visible
  }
  __syncthreads();
}

__device__ __forceinline__ void gates_phase(
    const u16* A0, int lda0, int k0,
    const u16* A1, int lda1, int k1,
    const u16* A2, int lda2,
    const u16* __restrict__ Wpack, int KT, int nkt,
    float* __restrict__ Cpart, int bid)
{
  const int tid = threadIdx.x;
  const int w = tid >> 6, lane = tid & 63;
  const int ksplit = bid >> 6;
  const int ngrp = bid & 63;
  const int ntile = ngrp * 4 + w;
  const int kt0 = ksplit * nkt;
  const int mrow = lane & 15;
  const int ksub = (lane >> 4) * 8;
  const int b01 = k0, b12 = k0 + k1;
  f32x4 acc0 = {0.f, 0.f, 0.f, 0.f};
  f32x4 acc1 = acc0, acc2 = acc0, acc3 = acc0;
  for (int kt = kt0; kt < kt0 + nkt; kt++) {
    int kb = kt * 32;
    const u16* Ap; int lda;
    if (kb < b01)      { Ap = A0; lda = lda0; }
    else if (kb < b12) { Ap = A1; lda = lda1; kb -= b01; }
    else               { Ap = A2; lda = lda2; kb -= b12; }
    const u16* abase = Ap + (size_t)mrow * lda + kb + ksub;
    bf16x8 bv = ldbf8(Wpack + ((size_t)(ntile * KT + kt) * 64 + lane) * 8);
    bf16x8 a0 = ldbf8(abase);
    bf16x8 a1 = ldbf8(abase + 16 * lda);
    bf16x8 a2 = ldbf8(abase + 32 * lda);
    bf16x8 a3 = ldbf8(abase + 48 * lda);
    acc0 = __builtin_amdgcn_mfma_f32_16x16x32_bf16(a0, bv, acc0, 0, 0, 0);
    acc1 = __builtin_amdgcn_mfma_f32_16x16x32_bf16(a1, bv, acc1, 0, 0, 0);
    acc2 = __builtin_amdgcn_mfma_f32_16x16x32_bf16(a2, bv, acc2, 0, 0, 0);
    acc3 = __builtin_amdgcn_mfma_f32_16x16x32_bf16(a3, bv, acc3, 0, 0, 0);
  }
  float* C = Cpart + (size_t)ksplit * (64 * 4096);
  const int n = ntile * 16 + (lane & 15);
  const int rb = (lane >> 4) * 4;
#pragma unroll
  for (int r = 0; r < 4; r++) {
    C[(size_t)(0 + rb + r) * 4096 + n]  = acc0[r];
    C[(size_t)(16 + rb + r) * 4096 + n] = acc1[r];
    C[(size_t)(32 + rb + r) * 4096 + n] = acc2[r];
    C[(size_t)(48 + rb + r) * 4096 + n] = acc3[r];
  }
}

__global__ __launch_bounds__(256, 2) void decoder_persist(
    const float* __restrict__ enc, const int* __restrict__ lens,
    const u16* __restrict__ xs_bf, const float* __restrict__ pmT,
    const u16* __restrict__ Wa_pack, const u16* __restrict__ Wd_pack,
    const float* __restrict__ b_a, const float* __restrict__ b_d,
    const float* __restrict__ Wq, const float* __restrict__ Wconv,
    const float* __restrict__ Wloc, const float* __restrict__ vvec,
    const float* __restrict__ Wp, const float* __restrict__ bp,
    float* __restrict__ ah, float* __restrict__ ac,
    float* __restrict__ dh, float* __restrict__ dc,
    float* __restrict__ actx, float* __restrict__ aw, float* __restrict__ awcum,
    u16* __restrict__ ah_bf, u16* __restrict__ dh_bf, u16* __restrict__ actx_bf,
    float* __restrict__ ga, float* __restrict__ gd,
    float* __restrict__ convG, unsigned* __restrict__ bar,
    float* __restrict__ outsOut, float* __restrict__ alignsOut)
{
  __shared__ Smem sm;
  const int bid = blockIdx.x;
  const int tid = threadIdx.x;
  unsigned k = 0;

  for (int t = 0; t <= T_OUTT; t++) {
    // ---- Phase A: gatesA(t) [0-447] + lstm_actD(t-1) [448-511] ----
    if (t < T_OUTT && bid < 448) {
      gates_phase(xs_bf + (size_t)t * 64 * 256, 256, 256,
                  actx_bf, 512, 512, ah_bf, 1024,
                  Wa_pack, 56, 8, ga, bid);
    } else if (bid >= 448 && t > 0) {
      int b2 = bid - 448;
      int j = tid * 4;
      float4 gi = {0,0,0,0}, gf = gi, gg = gi, go = gi;
#pragma unroll
      for (int s = 0; s < 8; s++) {
        const float* g = gd + (size_t)s * (64 * 4096) + (size_t)b2 * 4096 + j;
        float4 v;
        v = *(const float4*)(g);        gi.x+=v.x; gi.y+=v.y; gi.z+=v.z; gi.w+=v.w;
        v = *(const float4*)(g + 1024); gf.x+=v.x; gf.y+=v.y; gf.z+=v.z; gf.w+=v.w;
        v = *(const float4*)(g + 2048); gg.x+=v.x; gg.y+=v.y; gg.z+=v.z; gg.w+=v.w;
        v = *(const float4*)(g + 3072); go.x+=v.x; go.y+=v.y; go.z+=v.z; go.w+=v.w;
      }
      float4 bi = *(const float4*)(b_d + j);
      float4 bf = *(const float4*)(b_d + 1024 + j);
      float4 bg = *(const float4*)(b_d + 2048 + j);
      float4 bo = *(const float4*)(b_d + 3072 + j);
      int idx = b2 * 1024 + j;
#pragma unroll
      for (int q = 0; q < 4; q++) {
        float i_ = ((const float*)&gi)[q] + ((const float*)&bi)[q];
        float f_ = ((const float*)&gf)[q] + ((const float*)&bf)[q];
        float g_ = ((const float*)&gg)[q] + ((const float*)&bg)[q];
        float o_ = ((const float*)&go)[q] + ((const float*)&bo)[q];
        float cn = sigf(f_) * dc[idx + q] + sigf(i_) * tanhf(g_);
        dc[idx + q] = cn;
        float hn = sigf(o_) * tanhf(cn);
        dh[idx + q] = hn;
        dh_bf[idx + q] = f2bf(hn);
      }
    }
    k++; gbar(bar, k);

    // ---- Phase B: lstm_actA(t)[0-255] + conv(t)[256-319] + outproj(t-1)[320-399] ----
    if (t < T_OUTT && bid < 256) {
      int idx = bid * 256 + tid;
      int b = idx >> 10, j = idx & 1023;
      const float* g0 = ga + (size_t)b * 4096;
      float gi = b_a[j], gf = b_a[j + 1024], gg = b_a[j + 2048], go = b_a[j + 3072];
#pragma unroll
      for (int s = 0; s < 7; s++) {
        const float* g = g0 + (size_t)s * (64 * 4096);
        gi += g[j]; gf += g[j + 1024]; gg += g[j + 2048]; go += g[j + 3072];
      }
      float cn = sigf(gf) * ac[idx] + sigf(gi) * tanhf(gg);
      ac[idx] = cn;
      float hn = sigf(go) * tanhf(cn);
      ah[idx] = hn;
      ah_bf[idx] = f2bf(hn);
    } else if (t < T_OUTT && bid >= 256 && bid < 320) {
      int b = bid - 256;
      if (tid < T_INN) {
        sm.u.conv.aS[tid] = aw[b * T_INN + tid];
        sm.u.conv.cS[tid] = awcum[b * T_INN + tid];
      }
      for (int i = tid; i < 1984; i += 256) sm.u.conv.wc[i] = Wconv[i];
      __syncthreads();
      if (tid < T_INN) {
        float acc[32];
#pragma unroll
        for (int f = 0; f < 32; f++) acc[f] = 0.f;
        for (int kk = 0; kk < 31; kk++) {
          int tt = tid + kk - 15;
          if (tt >= 0 && tt < T_INN) {
            float a = sm.u.conv.aS[tt], c = sm.u.conv.cS[tt];
#pragma unroll
            for (int f = 0; f < 32; f++)
              acc[f] += sm.u.conv.wc[f * 62 + kk] * a + sm.u.conv.wc[f * 62 + 31 + kk] * c;
          }
        }
        float4* dst = (float4*)(convG + ((size_t)b * T_INN + tid) * 32);
#pragma unroll
        for (int i = 0; i < 8; i++) {
          float4 v; v.x = acc[i*4]; v.y = acc[i*4+1]; v.z = acc[i*4+2]; v.w = acc[i*4+3];
          dst[i] = v;
        }
      }
    }
    if (t > 0 && bid >= 320 && bid < 400) {
      int ob = bid - 320;
      int oi = tid >> 2, kq = tid & 3;
      int o = ob * 64 + oi;
      int b = o / NMEL, m = o - b * NMEL;
      int k4 = kq * 96, k4end = k4 + 96;
      float s = 0.f;
      const float4* wp4 = (const float4*)(Wp + (size_t)m * 1536);
      const float4* dh4 = (const float4*)(dh + (size_t)b * 1024);
      const float4* cx4 = (const float4*)(actx + (size_t)b * 512);
      int kaend = k4end < 256 ? k4end : 256;
#pragma unroll 4
      for (int i = k4; i < kaend; i++) {
        float4 w = wp4[i], a = dh4[i];
        s += w.x * a.x + w.y * a.y + w.z * a.z + w.w * a.w;
      }
      int kbst = k4 > 256 ? k4 : 256;
#pragma unroll 4
      for (int i = kbst; i < k4end; i++) {
        float4 w = wp4[i], a = cx4[i - 256];
        s += w.x * a.x + w.y * a.y + w.z * a.z + w.w * a.w;
      }
      sm.u.op.red[tid] = s;
      __syncthreads();
      if (kq == 0) {
        float tot = sm.u.op.red[tid] + sm.u.op.red[tid + 1] + sm.u.op.red[tid + 2] +
                    sm.u.op.red[tid + 3] + bp[m];
        outsOut[((size_t)b * T_OUTT + (t - 1)) * NMEL + m] = tot;
      }
    }
    k++; gbar(bar, k);
    if (t == T_OUTT) break;

    // ---- Phase C: fused attention (pq+energies+softmax+context) [0-63] ----
    if (bid < 64) {
      const int b = bid;
      for (int i = tid; i < 1024; i += 256) sm.u.at.ahS[i] = ah[(size_t)b * 1024 + i];
      __syncthreads();
      {
        int a = tid >> 1, hf = tid & 1;
        const float4* wv = (const float4*)(Wq + (size_t)a * 1024 + hf * 512);
        const float4* hv = (const float4*)(sm.u.at.ahS + hf * 512);
        float s0 = 0.f, s1 = 0.f;
#pragma unroll 8
        for (int i = 0; i < 64; i++) {
          float4 w = wv[i], h = hv[i];
          s0 += w.x * h.x + w.y * h.y + w.z * h.z + w.w * h.w;
        }
#pragma unroll 8
        for (int i = 64; i < 128; i++) {
          float4 w = wv[i], h = hv[i];
          s1 += w.x * h.x + w.y * h.y + w.z * h.z + w.w * h.w;
        }
        sm.u.at.pp[tid] = s0 + s1;
      }
      __syncthreads();
      if (tid < 128) sm.u.at.pq[tid] = sm.u.at.pp[2 * tid] + sm.u.at.pp[2 * tid + 1];
      __syncthreads();
      float e = -3.0e38f;
      if (tid < T_INN) {
        float cv[32];
        const float4* cg4 = (const float4*)(convG + ((size_t)b * T_INN + tid) * 32);
#pragma unroll
        for (int i = 0; i < 8; i++) {
          float4 v = cg4[i];
          cv[i*4] = v.x; cv[i*4+1] = v.y; cv[i*4+2] = v.z; cv[i*4+3] = v.w;
        }
        const float* pm = pmT + (size_t)b * 128 * T_INN + tid;
        float acc = 0.f;
        for (int a = 0; a < 128; a++) {
          float x = sm.u.at.pq[a] + pm[(size_t)a * T_INN];
          const float* wl = Wloc + a * 32;   // uniform addr -> scalar loads
#pragma unroll
          for (int f = 0; f < 32; f++) x = fmaf(wl[f], cv[f], x);
          acc = fmaf(vvec[a], tanhf(x), acc);
        }
        e = (tid < lens[b]) ? acc : -100000000.0f;
      }
      sm.u.at.red[tid] = e;
      __syncthreads();
      for (int s2 = 128; s2 > 0; s2 >>= 1) {
        if (tid < s2) sm.u.at.red[tid] = fmaxf(sm.u.at.red[tid], sm.u.at.red[tid + s2]);
        __syncthreads();
      }
      float mx = sm.u.at.red[0];
      __syncthreads();
      float ex = (tid < T_INN) ? expf(e - mx) : 0.f;
      sm.u.at.red[tid] = ex;
      __syncthreads();
      for (int s2 = 128; s2 > 0; s2 >>= 1) {
        if (tid < s2) sm.u.at.red[tid] += sm.u.at.red[tid + s2];
        __syncthreads();
      }
      float inv = 1.0f / sm.u.at.red[0];
      if (tid < T_INN) {
        float aval = ex * inv;
        sm.u.at.awS[tid] = aval;
        aw[b * T_INN + tid] = aval;
        awcum[b * T_INN + tid] += aval;
        alignsOut[((size_t)b * T_OUTT + t) * T_INN + tid] = aval;
      }
      __syncthreads();
      {
        float s0 = 0.f, s1 = 0.f;
        const float* e0p = enc + (size_t)b * T_INN * DENC + tid;
#pragma unroll 4
        for (int tt = 0; tt < T_INN; tt++) {
          float awv = sm.u.at.awS[tt];
          s0 = fmaf(awv, e0p[(size_t)tt * DENC], s0);
          s1 = fmaf(awv, e0p[(size_t)tt * DENC + 256], s1);
        }
        actx[b * DENC + tid] = s0;
        actx[b * DENC + tid + 256] = s1;
        actx_bf[b * DENC + tid] = f2bf(s0);
        actx_bf[b * DENC + tid + 256] = f2bf(s1);
      }
    }
    k++; gbar(bar, k);

    // ---- Phase D: gatesD(t) [0-511] ----
    gates_phase(ah_bf, 1024, 1024, actx_bf, 512, 512, dh_bf, 1024,
                Wd_pack, 80, 10, gd, bid);
    k++; gbar(bar, k);
  }
}

// ============================ launcher ============================
extern "C" void kernel_launch(void* const* d_in, const int* in_sizes, int n_in,
                              void* d_out, int out_size, void* d_ws, size_t ws_size,
                              hipStream_t stream)
{
  const float* enc    = (const float*)d_in[0];
  const float* dec    = (const float*)d_in[1];
  const int*   lens   = (const int*)d_in[2];
  const float* W_p1   = (const float*)d_in[3];
  const float* W_p2   = (const float*)d_in[4];
  const float* W_ih_a = (const float*)d_in[5];
  const float* W_hh_a = (const float*)d_in[6];
  const float* b_a    = (const float*)d_in[7];
  const float* Wq     = (const float*)d_in[8];
  const float* Wmem   = (const float*)d_in[9];
  const float* vvec   = (const float*)d_in[10];
  const float* Wconv  = (const float*)d_in[11];
  const float* Wloc   = (const float*)d_in[12];
  const float* W_ih_d = (const float*)d_in[13];
  const float* W_hh_d = (const float*)d_in[14];
  const float* b_d    = (const float*)d_in[15];
  const float* Wp     = (const float*)d_in[16];
  const float* bp     = (const float*)d_in[17];

  float* ws = (float*)d_ws;
  size_t off = 0;
  u16* xs_bf = (u16*)(ws + off); off += (size_t)T_OUTT * 64 * 256 / 2;
  float* pmT = ws + off; off += (size_t)64 * 128 * T_INN;
  u16* Wa_pack = (u16*)(ws + off); off += (size_t)4096 * 1792 / 2;
  u16* Wd_pack = (u16*)(ws + off); off += (size_t)4096 * 2560 / 2;
  float* stateBase = ws + off;
  float* ah    = stateBase;
  float* ac    = ah + 65536;
  float* dh    = ac + 65536;
  float* dc    = dh + 65536;
  float* actx  = dc + 65536;
  float* aw    = actx + 32768;
  float* awcum = aw + 12800;
  u16* ah_bf   = (u16*)(awcum + 12800);
  u16* dh_bf   = ah_bf + 65536;
  u16* actx_bf = dh_bf + 65536;
  unsigned* bar = (unsigned*)(actx_bf + 32768);    // 512 u32 barrier state
  size_t stateFloats = 4 * 65536 + 32768 + 2 * 12800 + (65536 + 65536 + 32768) / 2 + 512;
  off += stateFloats;
  float* convG = ws + off; off += (size_t)64 * T_INN * 32;
  float* scratch = ws + off;   // max(h1 6.54M, ga 1.84M + gd 2.10M floats)
  float* h1  = scratch;
  float* pmt = scratch;
  float* ga  = scratch;
  float* gd  = scratch + (size_t)7 * 64 * 4096;

  float* outsOut   = (float*)d_out;
  float* alignsOut = outsOut + (size_t)BB * T_OUTT * NMEL;

  hipMemsetAsync(stateBase, 0, stateFloats * sizeof(float), stream);
  hipMemsetAsync(xs_bf, 0, (size_t)64 * 256 * sizeof(u16), stream);

  // ---- precompute ----
  {
    int tot;
    tot = 256 * 24 * 64;
    pack_w_kernel<<<(tot + 255) / 256, 256, 0, stream>>>(W_ih_a, Wa_pack, 768, 24, 0, 56, tot);
    tot = 256 * 32 * 64;
    pack_w_kernel<<<(tot + 255) / 256, 256, 0, stream>>>(W_hh_a, Wa_pack, 1024, 32, 24, 56, tot);
    tot = 256 * 48 * 64;
    pack_w_kernel<<<(tot + 255) / 256, 256, 0, stream>>>(W_ih_d, Wd_pack, 1536, 48, 0, 80, tot);
    tot = 256 * 32 * 64;
    pack_w_kernel<<<(tot + 255) / 256, 256, 0, stream>>>(W_hh_d, Wd_pack, 1024, 32, 48, 80, tot);
  }
  gemm_pre_kernel<<<dim3(4, 399), 256, 0, stream>>>(dec, 80, W_p1, 80, h1, nullptr, 256, 80, 1);
  gemm_pre_kernel<<<dim3(4, 399), 256, 0, stream>>>(h1, 256, W_p2, 256, nullptr, xs_bf + 64 * 256, 256, 256, 1);
  gemm_pre_kernel<<<dim3(2, 200), 256, 0, stream>>>(enc, 512, Wmem, 512, pmt, nullptr, 128, 512, 0);
  transpose_pm_kernel<<<dim3(7, 4, 64), dim3(32, 8), 0, stream>>>(pmt, pmT);

  // ---- persistent decode loop (single launch, 1602 grid barriers) ----
  decoder_persist<<<NBLK, 256, 0, stream>>>(
      enc, lens, xs_bf, pmT, Wa_pack, Wd_pack, b_a, b_d,
      Wq, Wconv, Wloc, vvec, Wp, bp,
      ah, ac, dh, dc, actx, aw, awcum, ah_bf, dh_bf, actx_bf,
      ga, gd, convG, bar, outsOut, alignsOut);
}

// Round 5
// 98193.634 us; speedup vs baseline: 2.5323x; 1.0589x over previous
//
#include <hip/hip_runtime.h>
#include <cstddef>
#include <cstdint>

#define T_INN 200
#define T_OUTT 400
#define BB 64
#define DENC 512
#define NMEL 80
#define NBLK 512

typedef unsigned short u16;
typedef unsigned long long u64t;
typedef __bf16 bf16x8 __attribute__((ext_vector_type(8)));
typedef float f32x4 __attribute__((ext_vector_type(4)));

__device__ __forceinline__ float sigf(float x) { return 1.0f / (1.0f + expf(-x)); }

__device__ __forceinline__ u16 f2bf(float f) {
  unsigned u = __float_as_uint(f);
  unsigned r = u + 0x7fffu + ((u >> 16) & 1u);
  return (u16)(r >> 16);
}
__device__ __forceinline__ unsigned packbf2(float a, float b) {
  return (unsigned)f2bf(a) | ((unsigned)f2bf(b) << 16);
}

// ---- relaxed agent-scope atomic access (sc-bit LLC ops, NO fences) ----
__device__ __forceinline__ float ldAf(const float* p) {
  return __hip_atomic_load(p, __ATOMIC_RELAXED, __HIP_MEMORY_SCOPE_AGENT);
}
__device__ __forceinline__ void stAf(float* p, float v) {
  __hip_atomic_store(p, v, __ATOMIC_RELAXED, __HIP_MEMORY_SCOPE_AGENT);
}
__device__ __forceinline__ float2 ldA2(const float* p) {
  u64t u = __hip_atomic_load((const u64t*)p, __ATOMIC_RELAXED, __HIP_MEMORY_SCOPE_AGENT);
  union { u64t u; float2 f; } c; c.u = u; return c.f;
}
__device__ __forceinline__ void stA2(float* p, float x, float y) {
  union { u64t u; float2 f; } c; c.f = make_float2(x, y);
  __hip_atomic_store((u64t*)p, c.u, __ATOMIC_RELAXED, __HIP_MEMORY_SCOPE_AGENT);
}
__device__ __forceinline__ u64t ldA8u(const void* p) {
  return __hip_atomic_load((const u64t*)p, __ATOMIC_RELAXED, __HIP_MEMORY_SCOPE_AGENT);
}
__device__ __forceinline__ void stA4u(void* p, unsigned v) {
  __hip_atomic_store((unsigned*)p, v, __ATOMIC_RELAXED, __HIP_MEMORY_SCOPE_AGENT);
}
__device__ __forceinline__ void stA8u(void* p, u64t v) {
  __hip_atomic_store((u64t*)p, v, __ATOMIC_RELAXED, __HIP_MEMORY_SCOPE_AGENT);
}

// ============================ precompute kernels ============================
__global__ __launch_bounds__(256) void gemm_pre_kernel(
    const float* __restrict__ A, int lda, const float* __restrict__ W, int ldw,
    float* __restrict__ C, u16* __restrict__ Cbf, int ldc, int K, int relu)
{
  __shared__ float As[16][66];
  __shared__ float Ws[16][66];
  const int tid = threadIdx.x;
  const int tn = tid & 15, tm = tid >> 4;
  const int n0 = blockIdx.x * 64;
  const int m0 = blockIdx.y * 64;
  float acc[4][4] = {{0.f}};
  for (int kt = 0; kt < K; kt += 16) {
#pragma unroll
    for (int i = 0; i < 4; i++) {
      int e = tid + 256 * i;
      int m = e >> 4, kk = e & 15;
      As[kk][m] = A[(size_t)(m0 + m) * lda + kt + kk];
    }
#pragma unroll
    for (int i = 0; i < 4; i++) {
      int e = tid + 256 * i;
      int n = e >> 4, kk = e & 15;
      Ws[kk][n] = W[(size_t)(n0 + n) * ldw + kt + kk];
    }
    __syncthreads();
#pragma unroll
    for (int kk = 0; kk < 16; kk++) {
      float2 a01 = *(const float2*)&As[kk][tm * 4];
      float2 a23 = *(const float2*)&As[kk][tm * 4 + 2];
      float2 w01 = *(const float2*)&Ws[kk][tn * 4];
      float2 w23 = *(const float2*)&Ws[kk][tn * 4 + 2];
      float a[4] = {a01.x, a01.y, a23.x, a23.y};
      float w[4] = {w01.x, w01.y, w23.x, w23.y};
#pragma unroll
      for (int mi = 0; mi < 4; mi++)
#pragma unroll
        for (int ni = 0; ni < 4; ni++)
          acc[mi][ni] = fmaf(a[mi], w[ni], acc[mi][ni]);
    }
    __syncthreads();
  }
#pragma unroll
  for (int mi = 0; mi < 4; mi++) {
    int m = m0 + tm * 4 + mi;
    float v0 = acc[mi][0], v1 = acc[mi][1], v2 = acc[mi][2], v3 = acc[mi][3];
    if (relu) {
      v0 = fmaxf(v0, 0.f); v1 = fmaxf(v1, 0.f);
      v2 = fmaxf(v2, 0.f); v3 = fmaxf(v3, 0.f);
    }
    if (Cbf) {
      u16* p = Cbf + (size_t)m * ldc + n0 + tn * 4;
      p[0] = f2bf(v0); p[1] = f2bf(v1); p[2] = f2bf(v2); p[3] = f2bf(v3);
    } else {
      float4 vv; vv.x = v0; vv.y = v1; vv.z = v2; vv.w = v3;
      *(float4*)&C[(size_t)m * ldc + n0 + tn * 4] = vv;
    }
  }
}

__global__ __launch_bounds__(256) void pack_w_kernel(
    const float* __restrict__ W, u16* __restrict__ P,
    int K, int KTl, int ktOff, int KTtot, int total)
{
  int slot = blockIdx.x * 256 + threadIdx.x;
  if (slot >= total) return;
  int lane = slot & 63;
  int ktl = (slot >> 6) % KTl;
  int nt = slot / (64 * KTl);
  int n = nt * 16 + (lane & 15);
  int k = ktl * 32 + (lane >> 4) * 8;
  const float* src = W + (size_t)n * K + k;
  u16 tmp[8];
#pragma unroll
  for (int i = 0; i < 8; i++) tmp[i] = f2bf(src[i]);
  u16* dst = P + ((size_t)(nt * KTtot + (ktl + ktOff)) * 64 + lane) * 8;
  *(uint4*)dst = *(const uint4*)tmp;
}

__global__ void transpose_pm_kernel(const float* __restrict__ pm, float* __restrict__ pmT)
{
  int b = blockIdx.z;
  int tT = blockIdx.x * 32, aT = blockIdx.y * 32;
  __shared__ float tile[32][33];
  int tx = threadIdx.x, ty = threadIdx.y;
#pragma unroll
  for (int i = 0; i < 4; i++) {
    int t = tT + ty + i * 8;
    int a = aT + tx;
    if (t < T_INN) tile[ty + i * 8][tx] = pm[((size_t)b * T_INN + t) * 128 + a];
  }
  __syncthreads();
#pragma unroll
  for (int i = 0; i < 4; i++) {
    int a = aT + ty + i * 8;
    int t = tT + tx;
    if (t < T_INN) pmT[((size_t)b * 128 + a) * T_INN + t] = tile[tx][ty + i * 8];
  }
}

// ============================ persistent decoder ============================
// 512 blocks x 256 threads = 2 blocks/CU (LDS 58.4KB/block -> 116.8 <= 160KB).

struct __align__(16) Smem {
  union {
    u16 astage[64 * 456];   // 58368 B: A-chunk staging for gate GEMMs
    struct { float aS[T_INN]; float cS[T_INN]; float wc[1984]; } conv;
    struct { float ahS[1024]; float pp[256]; float pq[128]; float red[256]; float awS[256]; } at;
    struct { float red[256]; } op;
  } u;
};

// Fence-free grid barrier: two-level monotonic relaxed counters + relaxed
// polls. Correctness: all cross-block data uses agent-scope atomics (LLC
// coherent); __syncthreads drains each thread's stores (vmcnt) before the
// arrival RMW, so LLC-visibility happens-before arrival.
__device__ __forceinline__ void gbar(unsigned* bar, unsigned k)
{
  __syncthreads();
  if (threadIdx.x == 0) {
    asm volatile("" ::: "memory");
    const unsigned grp = blockIdx.x >> 6;
    unsigned* gen  = bar;                 // line 0
    unsigned* mcnt = bar + 32;            // line 1
    unsigned* ggen = bar + 64  + grp * 32;
    unsigned* gcnt = bar + 320 + grp * 32;
    unsigned a = __hip_atomic_fetch_add(gcnt, 1u, __ATOMIC_RELAXED, __HIP_MEMORY_SCOPE_AGENT);
    if (a == k * 64u - 1u) {   // group finisher
      unsigned m = __hip_atomic_fetch_add(mcnt, 1u, __ATOMIC_RELAXED, __HIP_MEMORY_SCOPE_AGENT);
      if (m == k * 8u - 1u) {
        __hip_atomic_store(gen, k, __ATOMIC_RELAXED, __HIP_MEMORY_SCOPE_AGENT);
      } else {
        while (__hip_atomic_load(gen, __ATOMIC_RELAXED, __HIP_MEMORY_SCOPE_AGENT) < k)
          __builtin_amdgcn_s_sleep(2);
      }
      __hip_atomic_store(ggen, k, __ATOMIC_RELAXED, __HIP_MEMORY_SCOPE_AGENT);
    } else {
      while (__hip_atomic_load(ggen, __ATOMIC_RELAXED, __HIP_MEMORY_SCOPE_AGENT) < k)
        __builtin_amdgcn_s_sleep(2);
    }
    asm volatile("" ::: "memory");
  }
  __syncthreads();
}

// Gate GEMM phase: stage A-chunk (3 bf16 segments) into LDS via 8B agent
// atomics, then MFMA with weights from (L2-cached) packed layout.
__device__ __forceinline__ void gates_ph(
    const u16* __restrict__ S0, int lda0, int k0,
    const u16* __restrict__ S1, int lda1, int k1,
    const u16* __restrict__ S2, int lda2,
    const u16* __restrict__ Wpack, int KTtot,
    int ksplit, int nkt, int ntile0, int nstep,
    int kchunk, int stridew, int qpr, int qdiv, int qmod,
    float* __restrict__ Cout, u16* lds)
{
  const int tid = threadIdx.x;
  const int kbeg = ksplit * nkt * 32;
  {
    int row = tid / qpr, col = tid - row * qpr;
    const int b01 = k0, b12 = k0 + k1;
    const int iters = (64 * qpr) >> 8;
    for (int i = 0; i < iters; i++) {
      int c = kbeg + col * 4;
      const u16* src;
      if (c < b01)      src = S0 + (size_t)row * lda0 + c;
      else if (c < b12) src = S1 + (size_t)row * lda1 + (c - b01);
      else              src = S2 + (size_t)row * lda2 + (c - b12);
      u64t v = ldA8u(src);
      *(u64t*)&lds[row * stridew + col * 4] = v;
      col += qmod; row += qdiv;
      if (col >= qpr) { col -= qpr; row += 1; }
    }
  }
  __syncthreads();
  const int w = tid >> 6, lane = tid & 63;
  const int mrow = lane & 15, ksub = (lane >> 4) * 8;
  const u16* lbase = lds + mrow * stridew + ksub;
  for (int nt = 0; nt < nstep; nt++) {
    int ntile = ntile0 + w * nstep + nt;
    f32x4 acc0 = {0.f, 0.f, 0.f, 0.f};
    f32x4 acc1 = acc0, acc2 = acc0, acc3 = acc0;
    const u16* wp = Wpack + ((size_t)(ntile * KTtot + ksplit * nkt) * 64 + lane) * 8;
    for (int kt = 0; kt < nkt; kt++) {
      const u16* lb = lbase + kt * 32;
      bf16x8 a0 = *(const bf16x8*)(lb);
      bf16x8 a1 = *(const bf16x8*)(lb + 16 * stridew);
      bf16x8 a2 = *(const bf16x8*)(lb + 32 * stridew);
      bf16x8 a3 = *(const bf16x8*)(lb + 48 * stridew);
      bf16x8 bv = *(const bf16x8*)(wp + (size_t)kt * 64 * 8);
      acc0 = __builtin_amdgcn_mfma_f32_16x16x32_bf16(a0, bv, acc0, 0, 0, 0);
      acc1 = __builtin_amdgcn_mfma_f32_16x16x32_bf16(a1, bv, acc1, 0, 0, 0);
      acc2 = __builtin_amdgcn_mfma_f32_16x16x32_bf16(a2, bv, acc2, 0, 0, 0);
      acc3 = __builtin_amdgcn_mfma_f32_16x16x32_bf16(a3, bv, acc3, 0, 0, 0);
    }
    const int n = ntile * 16 + mrow;
    const int rb = (lane >> 4) * 4;
#pragma unroll
    for (int r = 0; r < 4; r++) {
      stAf(Cout + (size_t)(0 + rb + r) * 4096 + n,  acc0[r]);
      stAf(Cout + (size_t)(16 + rb + r) * 4096 + n, acc1[r]);
      stAf(Cout + (size_t)(32 + rb + r) * 4096 + n, acc2[r]);
      stAf(Cout + (size_t)(48 + rb + r) * 4096 + n, acc3[r]);
    }
  }
}

__global__ __launch_bounds__(256, 2) void decoder_persist(
    const float* __restrict__ enc, const int* __restrict__ lens,
    const u16* __restrict__ xs_bf, const float* __restrict__ pmT,
    const u16* __restrict__ Wa_pack, const u16* __restrict__ Wd_pack,
    const float* __restrict__ b_a, const float* __restrict__ b_d,
    const float* __restrict__ Wq, const float* __restrict__ Wconv,
    const float* __restrict__ Wloc, const float* __restrict__ vvec,
    const float* __restrict__ Wp, const float* __restrict__ bp,
    float* __restrict__ ah, float* __restrict__ ac,
    float* __restrict__ dh, float* __restrict__ dc,
    float* __restrict__ actx, float* __restrict__ aw, float* __restrict__ awcum,
    u16* __restrict__ ah_bf, u16* __restrict__ dh_bf, u16* __restrict__ actx_bf,
    float* __restrict__ ga, float* __restrict__ gd,
    float* __restrict__ convG, unsigned* __restrict__ bar,
    float* __restrict__ outsOut, float* __restrict__ alignsOut)
{
  __shared__ Smem sm;
  const int bid = blockIdx.x;
  const int tid = threadIdx.x;
  unsigned k = 0;

  for (int t = 0; t <= T_OUTT; t++) {
    const int par_in  = (t + 1) & 1;   // context buffer of step t-1
    const int par_out = t & 1;

    // ---- P1: gatesA(t) [0-255] | gatesD(t-1) [256-511] ----
    if (t < T_OUTT && bid < 256) {
      int ks = bid >> 6, ng = bid & 63;
      gates_ph(xs_bf + (size_t)t * 64 * 256, 256, 256,
               actx_bf + par_in * 32768, 512, 512,
               ah_bf, 1024,
               Wa_pack, 56, ks, 14, ng * 4, 1,
               448, 456, 112, 2, 32,
               ga + (size_t)ks * 262144, sm.u.astage);
    } else if (bid >= 256 && t > 0) {
      int b2 = bid - 256, ks = b2 >> 5, ng = b2 & 31;
      gates_ph(ah_bf, 1024, 1024,
               actx_bf + par_in * 32768, 512, 512,
               dh_bf, 1024,
               Wd_pack, 80, ks, 10, ng * 8, 2,
               320, 328, 80, 3, 16,
               gd + (size_t)ks * 262144, sm.u.astage);
    }
    k++; gbar(bar, k);

    // ---- P2: lstmA(t) [0-127] | lstmD(t-1) [128-191] | conv(t) [192-255] ----
    if (t < T_OUTT && bid < 128) {
      int p = bid * 256 + tid;
      int b = p >> 9;
      int jj = (p & 511) * 2;
      const float* gbase = ga + (size_t)b * 4096 + jj;
      float2 sI = {0, 0}, sF = {0, 0}, sG = {0, 0}, sO = {0, 0};
#pragma unroll
      for (int s = 0; s < 4; s++) {
        const float* g = gbase + (size_t)s * 262144;
        float2 v;
        v = ldA2(g);        sI.x += v.x; sI.y += v.y;
        v = ldA2(g + 1024); sF.x += v.x; sF.y += v.y;
        v = ldA2(g + 2048); sG.x += v.x; sG.y += v.y;
        v = ldA2(g + 3072); sO.x += v.x; sO.y += v.y;
      }
      float2 bI = *(const float2*)(b_a + jj);
      float2 bF = *(const float2*)(b_a + 1024 + jj);
      float2 bG = *(const float2*)(b_a + 2048 + jj);
      float2 bO = *(const float2*)(b_a + 3072 + jj);
      int idx = b * 1024 + jj;
      float2 c0 = *(const float2*)(ac + idx);   // private to this block
      float cn0 = sigf(sF.x + bF.x) * c0.x + sigf(sI.x + bI.x) * tanhf(sG.x + bG.x);
      float cn1 = sigf(sF.y + bF.y) * c0.y + sigf(sI.y + bI.y) * tanhf(sG.y + bG.y);
      *(float2*)(ac + idx) = make_float2(cn0, cn1);
      float h0 = sigf(sO.x + bO.x) * tanhf(cn0);
      float h1 = sigf(sO.y + bO.y) * tanhf(cn1);
      stA2(ah + idx, h0, h1);
      stA4u(ah_bf + idx, packbf2(h0, h1));
    } else if (bid >= 128 && bid < 192 && t > 0) {
      int b2 = bid - 128;
      int j = tid * 4;
      float sI[4] = {0,0,0,0}, sF[4] = {0,0,0,0}, sG[4] = {0,0,0,0}, sO[4] = {0,0,0,0};
#pragma unroll
      for (int s = 0; s < 8; s++) {
        const float* g = gd + (size_t)s * 262144 + (size_t)b2 * 4096 + j;
        float2 v;
        v = ldA2(g);          sI[0] += v.x; sI[1] += v.y;
        v = ldA2(g + 2);      sI[2] += v.x; sI[3] += v.y;
        v = ldA2(g + 1024);   sF[0] += v.x; sF[1] += v.y;
        v = ldA2(g + 1026);   sF[2] += v.x; sF[3] += v.y;
        v = ldA2(g + 2048);   sG[0] += v.x; sG[1] += v.y;
        v = ldA2(g + 2050);   sG[2] += v.x; sG[3] += v.y;
        v = ldA2(g + 3072);   sO[0] += v.x; sO[1] += v.y;
        v = ldA2(g + 3074);   sO[2] += v.x; sO[3] += v.y;
      }
      int idx = b2 * 1024 + j;
      float4 c0 = *(const float4*)(dc + idx);   // private to this block
      float cn[4], hh[4];
      const float* cc = (const float*)&c0;
#pragma unroll
      for (int q = 0; q < 4; q++) {
        float i_ = sI[q] + b_d[j + q];
        float f_ = sF[q] + b_d[1024 + j + q];
        float g_ = sG[q] + b_d[2048 + j + q];
        float o_ = sO[q] + b_d[3072 + j + q];
        cn[q] = sigf(f_) * cc[q] + sigf(i_) * tanhf(g_);
        hh[q] = sigf(o_) * tanhf(cn[q]);
      }
      float4 cw; cw.x = cn[0]; cw.y = cn[1]; cw.z = cn[2]; cw.w = cn[3];
      *(float4*)(dc + idx) = cw;
      stA2(dh + idx, hh[0], hh[1]);
      stA2(dh + idx + 2, hh[2], hh[3]);
      stA8u(dh_bf + idx, (u64t)packbf2(hh[0], hh[1]) | ((u64t)packbf2(hh[2], hh[3]) << 32));
    } else if (bid >= 192 && bid < 256 && t < T_OUTT) {
      int b = bid - 192;
      if (tid < T_INN) {
        sm.u.conv.aS[tid] = ldAf(aw + b * T_INN + tid);
        sm.u.conv.cS[tid] = ldAf(awcum + b * T_INN + tid);
      }
      for (int i = tid; i < 1984; i += 256) sm.u.conv.wc[i] = Wconv[i];
      __syncthreads();
      if (tid < T_INN) {
        float acc[32];
#pragma unroll
        for (int f = 0; f < 32; f++) acc[f] = 0.f;
        for (int kk = 0; kk < 31; kk++) {
          int tt = tid + kk - 15;
          if (tt >= 0 && tt < T_INN) {
            float a = sm.u.conv.aS[tt], c = sm.u.conv.cS[tt];
#pragma unroll
            for (int f = 0; f < 32; f++)
              acc[f] += sm.u.conv.wc[f * 62 + kk] * a + sm.u.conv.wc[f * 62 + 31 + kk] * c;
          }
        }
        float* dst = convG + ((size_t)b * T_INN + tid) * 32;
#pragma unroll
        for (int i = 0; i < 16; i++) stA2(dst + 2 * i, acc[2 * i], acc[2 * i + 1]);
      }
    }
    k++; gbar(bar, k);

    // ---- P3: attention(t) [0-63] | outproj(t-1) [64-143] ----
    if (t < T_OUTT && bid < 64) {
      const int b = bid;
      for (int i = tid; i < 1024; i += 256) sm.u.at.ahS[i] = ldAf(ah + (size_t)b * 1024 + i);
      __syncthreads();
      {
        int a = tid >> 1, hf = tid & 1;
        const float4* wv = (const float4*)(Wq + (size_t)a * 1024 + hf * 512);
        const float4* hv = (const float4*)(sm.u.at.ahS + hf * 512);
        float s0 = 0.f, s1 = 0.f;
#pragma unroll 8
        for (int i = 0; i < 64; i++) {
          float4 w = wv[i], h = hv[i];
          s0 += w.x * h.x + w.y * h.y + w.z * h.z + w.w * h.w;
        }
#pragma unroll 8
        for (int i = 64; i < 128; i++) {
          float4 w = wv[i], h = hv[i];
          s1 += w.x * h.x + w.y * h.y + w.z * h.z + w.w * h.w;
        }
        sm.u.at.pp[tid] = s0 + s1;
      }
      __syncthreads();
      if (tid < 128) sm.u.at.pq[tid] = sm.u.at.pp[2 * tid] + sm.u.at.pp[2 * tid + 1];
      __syncthreads();
      float e = -3.0e38f;
      if (tid < T_INN) {
        float cv[32];
        const float* cg = convG + ((size_t)b * T_INN + tid) * 32;
#pragma unroll
        for (int i = 0; i < 16; i++) {
          float2 v = ldA2(cg + 2 * i);
          cv[2 * i] = v.x; cv[2 * i + 1] = v.y;
        }
        const float* pm = pmT + (size_t)b * 128 * T_INN + tid;
        float acc = 0.f;
        for (int a = 0; a < 128; a++) {
          float x = sm.u.at.pq[a] + pm[(size_t)a * T_INN];
          const float* wl = Wloc + a * 32;
#pragma unroll
          for (int f = 0; f < 32; f++) x = fmaf(wl[f], cv[f], x);
          acc = fmaf(vvec[a], tanhf(x), acc);
        }
        e = (tid < lens[b]) ? acc : -100000000.0f;
      }
      sm.u.at.red[tid] = e;
      __syncthreads();
      for (int s2 = 128; s2 > 0; s2 >>= 1) {
        if (tid < s2) sm.u.at.red[tid] = fmaxf(sm.u.at.red[tid], sm.u.at.red[tid + s2]);
        __syncthreads();
      }
      float mx = sm.u.at.red[0];
      __syncthreads();
      float ex = (tid < T_INN) ? expf(e - mx) : 0.f;
      sm.u.at.red[tid] = ex;
      __syncthreads();
      for (int s2 = 128; s2 > 0; s2 >>= 1) {
        if (tid < s2) sm.u.at.red[tid] += sm.u.at.red[tid + s2];
        __syncthreads();
      }
      float inv = 1.0f / sm.u.at.red[0];
      if (tid < T_INN) {
        float aval = ex * inv;
        sm.u.at.awS[tid] = aval;
        stAf(aw + b * T_INN + tid, aval);
        float oldc = ldAf(awcum + b * T_INN + tid);
        stAf(awcum + b * T_INN + tid, oldc + aval);
        alignsOut[((size_t)b * T_OUTT + t) * T_INN + tid] = aval;
      } else if (tid < 256) {
        sm.u.at.awS[tid] = 0.f;
      }
      __syncthreads();
      {
        float s0 = 0.f, s1 = 0.f;
        const float* e0p = enc + (size_t)b * T_INN * DENC + 2 * tid;
#pragma unroll 4
        for (int tt = 0; tt < T_INN; tt++) {
          float awv = sm.u.at.awS[tt];
          float2 ev = *(const float2*)(e0p + (size_t)tt * DENC);
          s0 = fmaf(awv, ev.x, s0);
          s1 = fmaf(awv, ev.y, s1);
        }
        stA2(actx + par_out * 32768 + b * DENC + 2 * tid, s0, s1);
        stA4u(actx_bf + par_out * 32768 + b * DENC + 2 * tid, packbf2(s0, s1));
      }
    }
    if (t > 0 && bid >= 64 && bid < 144) {
      int ob = bid - 64;
      int oi = tid >> 2, kq = tid & 3;
      int o = ob * 64 + oi;
      int b = o / NMEL, m = o - b * NMEL;
      int k4 = kq * 96, k4end = k4 + 96;   // in float4 units over 384 (=1536 f)
      float s = 0.f;
      const float4* wp4 = (const float4*)(Wp + (size_t)m * 1536);
      const float* dhb = dh + (size_t)b * 1024;
      const float* cxb = actx + par_in * 32768 + (size_t)b * 512;
      int kaend = k4end < 256 ? k4end : 256;
      for (int i = k4; i < kaend; i++) {
        float4 w = wp4[i];
        float2 a0 = ldA2(dhb + i * 4);
        float2 a1 = ldA2(dhb + i * 4 + 2);
        s += w.x * a0.x + w.y * a0.y + w.z * a1.x + w.w * a1.y;
      }
      int kbst = k4 > 256 ? k4 : 256;
      for (int i = kbst; i < k4end; i++) {
        float4 w = wp4[i];
        float2 a0 = ldA2(cxb + (i - 256) * 4);
        float2 a1 = ldA2(cxb + (i - 256) * 4 + 2);
        s += w.x * a0.x + w.y * a0.y + w.z * a1.x + w.w * a1.y;
      }
      sm.u.op.red[tid] = s;
      __syncthreads();
      if (kq == 0) {
        float tot = sm.u.op.red[tid] + sm.u.op.red[tid + 1] + sm.u.op.red[tid + 2] +
                    sm.u.op.red[tid + 3] + bp[m];
        outsOut[((size_t)b * T_OUTT + (t - 1)) * NMEL + m] = tot;
      }
    }
    k++; gbar(bar, k);
  }
}

// ============================ launcher ============================
extern "C" void kernel_launch(void* const* d_in, const int* in_sizes, int n_in,
                              void* d_out, int out_size, void* d_ws, size_t ws_size,
                              hipStream_t stream)
{
  const float* enc    = (const float*)d_in[0];
  const float* dec    = (const float*)d_in[1];
  const int*   lens   = (const int*)d_in[2];
  const float* W_p1   = (const float*)d_in[3];
  const float* W_p2   = (const float*)d_in[4];
  const float* W_ih_a = (const float*)d_in[5];
  const float* W_hh_a = (const float*)d_in[6];
  const float* b_a    = (const float*)d_in[7];
  const float* Wq     = (const float*)d_in[8];
  const float* Wmem   = (const float*)d_in[9];
  const float* vvec   = (const float*)d_in[10];
  const float* Wconv  = (const float*)d_in[11];
  const float* Wloc   = (const float*)d_in[12];
  const float* W_ih_d = (const float*)d_in[13];
  const float* W_hh_d = (const float*)d_in[14];
  const float* b_d    = (const float*)d_in[15];
  const float* Wp     = (const float*)d_in[16];
  const float* bp     = (const float*)d_in[17];

  float* ws = (float*)d_ws;
  size_t off = 0;
  u16* xs_bf = (u16*)(ws + off); off += (size_t)T_OUTT * 64 * 256 / 2;     // 3.277M f
  float* pmT = ws + off; off += (size_t)64 * 128 * T_INN;                  // 1.638M f
  u16* Wa_pack = (u16*)(ws + off); off += (size_t)4096 * 1792 / 2;         // 3.670M f
  u16* Wd_pack = (u16*)(ws + off); off += (size_t)4096 * 2560 / 2;         // 5.243M f
  float* stateBase = ws + off;
  float* ah    = stateBase;                       // 65536
  float* ac    = ah + 65536;                      // 65536
  float* dh    = ac + 65536;                      // 65536
  float* dc    = dh + 65536;                      // 65536
  float* actx  = dc + 65536;                      // 2 x 32768
  float* aw    = actx + 65536;                    // 12800
  float* awcum = aw + 12800;                      // 12800
  u16* ah_bf   = (u16*)(awcum + 12800);           // 65536 u16
  u16* dh_bf   = ah_bf + 65536;                   // 65536 u16
  u16* actx_bf = dh_bf + 65536;                   // 2 x 32768 u16
  unsigned* bar = (unsigned*)(actx_bf + 65536);   // 1024 u32
  size_t stateFloats = 5 * 65536 + 2 * 12800 + (65536 + 65536 + 65536) / 2 + 1024;
  off += stateFloats;
  float* convG = ws + off; off += (size_t)64 * T_INN * 32;                 // 409600
  float* scratch = ws + off;   // precompute h1 (6.54M) overlaps ga+gd (3.15M)
  float* h1  = scratch;
  float* pmt = scratch;
  float* ga  = scratch;                              // 4*64*4096 = 1.049M
  float* gd  = scratch + (size_t)4 * 64 * 4096;      // 8*64*4096 = 2.097M

  float* outsOut   = (float*)d_out;
  float* alignsOut = outsOut + (size_t)BB * T_OUTT * NMEL;

  hipMemsetAsync(stateBase, 0, stateFloats * sizeof(float), stream);
  hipMemsetAsync(xs_bf, 0, (size_t)64 * 256 * sizeof(u16), stream);

  // ---- precompute ----
  {
    int tot;
    tot = 256 * 24 * 64;
    pack_w_kernel<<<(tot + 255) / 256, 256, 0, stream>>>(W_ih_a, Wa_pack, 768, 24, 0, 56, tot);
    tot = 256 * 32 * 64;
    pack_w_kernel<<<(tot + 255) / 256, 256, 0, stream>>>(W_hh_a, Wa_pack, 1024, 32, 24, 56, tot);
    tot = 256 * 48 * 64;
    pack_w_kernel<<<(tot + 255) / 256, 256, 0, stream>>>(W_ih_d, Wd_pack, 1536, 48, 0, 80, tot);
    tot = 256 * 32 * 64;
    pack_w_kernel<<<(tot + 255) / 256, 256, 0, stream>>>(W_hh_d, Wd_pack, 1024, 32, 48, 80, tot);
  }
  gemm_pre_kernel<<<dim3(4, 399), 256, 0, stream>>>(dec, 80, W_p1, 80, h1, nullptr, 256, 80, 1);
  gemm_pre_kernel<<<dim3(4, 399), 256, 0, stream>>>(h1, 256, W_p2, 256, nullptr, xs_bf + 64 * 256, 256, 256, 1);
  gemm_pre_kernel<<<dim3(2, 200), 256, 0, stream>>>(enc, 512, Wmem, 512, pmt, nullptr, 128, 512, 0);
  transpose_pm_kernel<<<dim3(7, 4, 64), dim3(32, 8), 0, stream>>>(pmt, pmT);

  // ---- persistent decode loop (single launch, 1203 fence-free barriers) ----
  decoder_persist<<<NBLK, 256, 0, stream>>>(
      enc, lens, xs_bf, pmT, Wa_pack, Wd_pack, b_a, b_d,
      Wq, Wconv, Wloc, vvec, Wp, bp,
      ah, ac, dh, dc, actx, aw, awcum, ah_bf, dh_bf, actx_bf,
      ga, gd, convG, bar, outsOut, alignsOut);
}

// Round 6
// 80728.162 us; speedup vs baseline: 3.0802x; 1.2163x over previous
//
#include <hip/hip_runtime.h>
#include <cstddef>
#include <cstdint>

#define T_INN 200
#define T_OUTT 400
#define BB 64
#define DENC 512
#define NMEL 80
#define NBLK2 256

typedef unsigned short u16;
typedef unsigned long long u64t;
typedef __bf16 bf16x8 __attribute__((ext_vector_type(8)));
typedef float f32x4 __attribute__((ext_vector_type(4)));

__device__ __forceinline__ float sigf(float x) { return 1.0f / (1.0f + expf(-x)); }

__device__ __forceinline__ u16 f2bf(float f) {
  unsigned u = __float_as_uint(f);
  unsigned r = u + 0x7fffu + ((u >> 16) & 1u);
  return (u16)(r >> 16);
}
__device__ __forceinline__ unsigned packbf2(float a, float b) {
  return (unsigned)f2bf(a) | ((unsigned)f2bf(b) << 16);
}

// ---- relaxed agent-scope atomics (LLC-coherent, no cache-maintenance) ----
__device__ __forceinline__ float ldAf(const float* p) {
  return __hip_atomic_load(p, __ATOMIC_RELAXED, __HIP_MEMORY_SCOPE_AGENT);
}
__device__ __forceinline__ void stAf(float* p, float v) {
  __hip_atomic_store(p, v, __ATOMIC_RELAXED, __HIP_MEMORY_SCOPE_AGENT);
}
__device__ __forceinline__ float2 ldA2(const float* p) {
  u64t u = __hip_atomic_load((const u64t*)p, __ATOMIC_RELAXED, __HIP_MEMORY_SCOPE_AGENT);
  union { u64t u; float2 f; } c; c.u = u; return c.f;
}
__device__ __forceinline__ void stA2(float* p, float x, float y) {
  union { u64t u; float2 f; } c; c.f = make_float2(x, y);
  __hip_atomic_store((u64t*)p, c.u, __ATOMIC_RELAXED, __HIP_MEMORY_SCOPE_AGENT);
}
__device__ __forceinline__ u64t ldA8u(const void* p) {
  return __hip_atomic_load((const u64t*)p, __ATOMIC_RELAXED, __HIP_MEMORY_SCOPE_AGENT);
}
__device__ __forceinline__ void stA4u(void* p, unsigned v) {
  __hip_atomic_store((unsigned*)p, v, __ATOMIC_RELAXED, __HIP_MEMORY_SCOPE_AGENT);
}
__device__ __forceinline__ void atomAddF(float* p, float v) {
  (void)__hip_atomic_fetch_add(p, v, __ATOMIC_RELAXED, __HIP_MEMORY_SCOPE_AGENT);
}

// ============================ precompute kernels ============================
__global__ __launch_bounds__(256) void gemm_pre_kernel(
    const float* __restrict__ A, int lda, const float* __restrict__ W, int ldw,
    float* __restrict__ C, u16* __restrict__ Cbf, int ldc, int K, int relu)
{
  __shared__ float As[16][66];
  __shared__ float Ws[16][66];
  const int tid = threadIdx.x;
  const int tn = tid & 15, tm = tid >> 4;
  const int n0 = blockIdx.x * 64;
  const int m0 = blockIdx.y * 64;
  float acc[4][4] = {{0.f}};
  for (int kt = 0; kt < K; kt += 16) {
#pragma unroll
    for (int i = 0; i < 4; i++) {
      int e = tid + 256 * i;
      int m = e >> 4, kk = e & 15;
      As[kk][m] = A[(size_t)(m0 + m) * lda + kt + kk];
    }
#pragma unroll
    for (int i = 0; i < 4; i++) {
      int e = tid + 256 * i;
      int n = e >> 4, kk = e & 15;
      Ws[kk][n] = W[(size_t)(n0 + n) * ldw + kt + kk];
    }
    __syncthreads();
#pragma unroll
    for (int kk = 0; kk < 16; kk++) {
      float2 a01 = *(const float2*)&As[kk][tm * 4];
      float2 a23 = *(const float2*)&As[kk][tm * 4 + 2];
      float2 w01 = *(const float2*)&Ws[kk][tn * 4];
      float2 w23 = *(const float2*)&Ws[kk][tn * 4 + 2];
      float a[4] = {a01.x, a01.y, a23.x, a23.y};
      float w[4] = {w01.x, w01.y, w23.x, w23.y};
#pragma unroll
      for (int mi = 0; mi < 4; mi++)
#pragma unroll
        for (int ni = 0; ni < 4; ni++)
          acc[mi][ni] = fmaf(a[mi], w[ni], acc[mi][ni]);
    }
    __syncthreads();
  }
#pragma unroll
  for (int mi = 0; mi < 4; mi++) {
    int m = m0 + tm * 4 + mi;
    float v0 = acc[mi][0], v1 = acc[mi][1], v2 = acc[mi][2], v3 = acc[mi][3];
    if (relu) {
      v0 = fmaxf(v0, 0.f); v1 = fmaxf(v1, 0.f);
      v2 = fmaxf(v2, 0.f); v3 = fmaxf(v3, 0.f);
    }
    if (Cbf) {
      u16* p = Cbf + (size_t)m * ldc + n0 + tn * 4;
      p[0] = f2bf(v0); p[1] = f2bf(v1); p[2] = f2bf(v2); p[3] = f2bf(v3);
    } else {
      float4 vv; vv.x = v0; vv.y = v1; vv.z = v2; vv.w = v3;
      *(float4*)&C[(size_t)m * ldc + n0 + tn * 4] = vv;
    }
  }
}

__global__ __launch_bounds__(256) void pack_w_kernel(
    const float* __restrict__ W, u16* __restrict__ P,
    int K, int KTl, int ktOff, int KTtot, int total)
{
  int slot = blockIdx.x * 256 + threadIdx.x;
  if (slot >= total) return;
  int lane = slot & 63;
  int ktl = (slot >> 6) % KTl;
  int nt = slot / (64 * KTl);
  int n = nt * 16 + (lane & 15);
  int k = ktl * 32 + (lane >> 4) * 8;
  const float* src = W + (size_t)n * K + k;
  u16 tmp[8];
#pragma unroll
  for (int i = 0; i < 8; i++) tmp[i] = f2bf(src[i]);
  u16* dst = P + ((size_t)(nt * KTtot + (ktl + ktOff)) * 64 + lane) * 8;
  *(uint4*)dst = *(const uint4*)tmp;
}

__global__ void transpose_pm_kernel(const float* __restrict__ pm, float* __restrict__ pmT)
{
  int b = blockIdx.z;
  int tT = blockIdx.x * 32, aT = blockIdx.y * 32;
  __shared__ float tile[32][33];
  int tx = threadIdx.x, ty = threadIdx.y;
#pragma unroll
  for (int i = 0; i < 4; i++) {
    int t = tT + ty + i * 8;
    int a = aT + tx;
    if (t < T_INN) tile[ty + i * 8][tx] = pm[((size_t)b * T_INN + t) * 128 + a];
  }
  __syncthreads();
#pragma unroll
  for (int i = 0; i < 4; i++) {
    int a = aT + ty + i * 8;
    int t = tT + tx;
    if (t < T_INN) pmT[((size_t)b * 128 + a) * T_INN + t] = tile[tx][ty + i * 8];
  }
}

// ============================ persistent decoder ============================
// 256 blocks x 1024 threads, 1 block/CU. Weights LDS-resident for all steps.
struct __align__(16) SmemW {
  u16 wA[8][7][64][8];     // 57344 B
  u16 wD[8][10][64][8];    // 81920 B
  union {
    u16 ast[64][184];      // 23552 B ; row stride 368 B (16B aligned, ~2-way banks)
    struct {
      float pq[128];
      float ep[4][256];
      float red[256];
      float awS[256];
      union { struct { float ahS[1088]; float pp[1024]; } q; } w;
    } at;
    struct { float aS[256]; float cS[256]; float wc[1984]; } conv;
    struct { float red[1024]; } op;
  } u;
};

// Fence-free grid barrier (256 blocks, 8 groups of 32, monotonic counters).
__device__ __forceinline__ void gbar(unsigned* bar, unsigned k)
{
  __syncthreads();
  if (threadIdx.x == 0) {
    asm volatile("" ::: "memory");
    const unsigned grp = blockIdx.x >> 5;
    unsigned* gen  = bar;
    unsigned* mcnt = bar + 32;
    unsigned* ggen = bar + 64  + grp * 32;
    unsigned* gcnt = bar + 384 + grp * 32;
    unsigned a = __hip_atomic_fetch_add(gcnt, 1u, __ATOMIC_RELAXED, __HIP_MEMORY_SCOPE_AGENT);
    if (a == k * 32u - 1u) {
      unsigned m = __hip_atomic_fetch_add(mcnt, 1u, __ATOMIC_RELAXED, __HIP_MEMORY_SCOPE_AGENT);
      if (m == k * 8u - 1u)
        __hip_atomic_store(gen, k, __ATOMIC_RELAXED, __HIP_MEMORY_SCOPE_AGENT);
      else
        while (__hip_atomic_load(gen, __ATOMIC_RELAXED, __HIP_MEMORY_SCOPE_AGENT) < k)
          __builtin_amdgcn_s_sleep(2);
      __hip_atomic_store(ggen, k, __ATOMIC_RELAXED, __HIP_MEMORY_SCOPE_AGENT);
    } else {
      while (__hip_atomic_load(ggen, __ATOMIC_RELAXED, __HIP_MEMORY_SCOPE_AGENT) < k)
        __builtin_amdgcn_s_sleep(2);
    }
    asm volatile("" ::: "memory");
  }
  __syncthreads();
}

// gatesA: concat A = [xs(256) | actx(512) | ah(1024)], block tile n=128, k=224.
__device__ __forceinline__ void gatesA_ph(
    SmemW& sm, int tid, int ng, int kc,
    const u16* __restrict__ xs_t, const u16* __restrict__ actx_b,
    const u16* __restrict__ ah_b, float* __restrict__ gap)
{
  const int w = tid >> 6, lane = tid & 63;
  const int nt = w & 7, mg = w >> 3;
  const int mrow = lane & 15, ksub = (lane >> 4) * 8;
  const int rb = (lane >> 4) * 4;
  f32x4 acc0 = {0.f, 0.f, 0.f, 0.f}, acc1 = acc0;
#pragma unroll
  for (int half = 0; half < 2; half++) {
    const int ncolg = half ? 24 : 32;
    const int cbase = kc * 224 + half * 128;
    __syncthreads();
    for (int s = tid; s < 64 * ncolg; s += 1024) {
      int row = s / ncolg, cg = s - row * ncolg;
      int c = cbase + cg * 4;
      u64t v;
      if (c < 256)      v = *(const u64t*)(xs_t + row * 256 + c);
      else if (c < 768) v = ldA8u(actx_b + row * 512 + (c - 256));
      else              v = ldA8u(ah_b + row * 1024 + (c - 768));
      *(u64t*)&sm.u.ast[row][cg * 4] = v;
    }
    __syncthreads();
    const int nkt = half ? 3 : 4;
    for (int ktl = 0; ktl < nkt; ktl++) {
      bf16x8 a0 = *(const bf16x8*)&sm.u.ast[mg * 32 + mrow][ktl * 32 + ksub];
      bf16x8 a1 = *(const bf16x8*)&sm.u.ast[mg * 32 + 16 + mrow][ktl * 32 + ksub];
      bf16x8 bv = *(const bf16x8*)&sm.wA[nt][half * 4 + ktl][lane][0];
      acc0 = __builtin_amdgcn_mfma_f32_16x16x32_bf16(a0, bv, acc0, 0, 0, 0);
      acc1 = __builtin_amdgcn_mfma_f32_16x16x32_bf16(a1, bv, acc1, 0, 0, 0);
    }
  }
  const int gn = (ng * 8 + nt) * 16 + mrow;
#pragma unroll
  for (int r = 0; r < 4; r++) {
    atomAddF(gap + (size_t)(mg * 32 + rb + r) * 4096 + gn, acc0[r]);
    atomAddF(gap + (size_t)(mg * 32 + 16 + rb + r) * 4096 + gn, acc1[r]);
  }
}

// gatesD: concat A = [ah(1024) | actx(512) | dh(1024)], block tile n=128, k=320.
__device__ __forceinline__ void gatesD_ph(
    SmemW& sm, int tid, int ng, int kc,
    const u16* __restrict__ ah_b, const u16* __restrict__ actx_b,
    const u16* __restrict__ dh_b, float* __restrict__ gdp)
{
  const int w = tid >> 6, lane = tid & 63;
  const int nt = w & 7, mg = w >> 3;
  const int mrow = lane & 15, ksub = (lane >> 4) * 8;
  const int rb = (lane >> 4) * 4;
  f32x4 acc0 = {0.f, 0.f, 0.f, 0.f}, acc1 = acc0;
#pragma unroll
  for (int half = 0; half < 2; half++) {
    const int cbase = kc * 320 + half * 160;
    __syncthreads();
    for (int s = tid; s < 64 * 40; s += 1024) {
      int row = s / 40, cg = s - row * 40;
      int c = cbase + cg * 4;
      u64t v;
      if (c < 1024)      v = ldA8u(ah_b + row * 1024 + c);
      else if (c < 1536) v = ldA8u(actx_b + row * 512 + (c - 1024));
      else               v = ldA8u(dh_b + row * 1024 + (c - 1536));
      *(u64t*)&sm.u.ast[row][cg * 4] = v;
    }
    __syncthreads();
    for (int ktl = 0; ktl < 5; ktl++) {
      bf16x8 a0 = *(const bf16x8*)&sm.u.ast[mg * 32 + mrow][ktl * 32 + ksub];
      bf16x8 a1 = *(const bf16x8*)&sm.u.ast[mg * 32 + 16 + mrow][ktl * 32 + ksub];
      bf16x8 bv = *(const bf16x8*)&sm.wD[nt][half * 5 + ktl][lane][0];
      acc0 = __builtin_amdgcn_mfma_f32_16x16x32_bf16(a0, bv, acc0, 0, 0, 0);
      acc1 = __builtin_amdgcn_mfma_f32_16x16x32_bf16(a1, bv, acc1, 0, 0, 0);
    }
  }
  const int gn = (ng * 8 + nt) * 16 + mrow;
#pragma unroll
  for (int r = 0; r < 4; r++) {
    atomAddF(gdp + (size_t)(mg * 32 + rb + r) * 4096 + gn, acc0[r]);
    atomAddF(gdp + (size_t)(mg * 32 + 16 + rb + r) * 4096 + gn, acc1[r]);
  }
}

__global__ __launch_bounds__(1024, 4) void decoder_persist(
    const float* __restrict__ enc, const int* __restrict__ lens,
    const u16* __restrict__ xs_bf, const float* __restrict__ pmT,
    const u16* __restrict__ Wa_pack, const u16* __restrict__ Wd_pack,
    const float* __restrict__ b_a, const float* __restrict__ b_d,
    const float* __restrict__ Wq, const float* __restrict__ Wconv,
    const float* __restrict__ Wloc, const float* __restrict__ vvec,
    const float* __restrict__ Wp, const float* __restrict__ bp,
    float* __restrict__ ah, float* __restrict__ ac,
    float* __restrict__ dh, float* __restrict__ dc,
    float* __restrict__ actx, float* __restrict__ aw, float* __restrict__ awcum,
    u16* __restrict__ ah_bf, u16* __restrict__ dh_bf, u16* __restrict__ actx_bf,
    float* __restrict__ ga, float* __restrict__ gd,
    float* __restrict__ convG, unsigned* __restrict__ bar,
    float* __restrict__ outsOut, float* __restrict__ alignsOut)
{
  __shared__ SmemW sm;
  const int bid = blockIdx.x;
  const int tid = threadIdx.x;
  const int ng = bid & 31, kc = bid >> 5;
  unsigned k = 0;

  // ---- prologue: load this block's weight slices into LDS (once) ----
  for (int s = tid; s < 3584; s += 1024) {
    int nt2 = s / 448, r2 = s - nt2 * 448;
    int kt2 = r2 >> 6, lane2 = r2 & 63;
    uint4 v = *(const uint4*)(Wa_pack + (((size_t)(ng * 8 + nt2) * 56 + (kc * 7 + kt2)) * 64 + lane2) * 8);
    *(uint4*)&sm.wA[nt2][kt2][lane2][0] = v;
  }
  for (int s = tid; s < 5120; s += 1024) {
    int nt2 = s / 640, r2 = s - nt2 * 640;
    int kt2 = r2 >> 6, lane2 = r2 & 63;
    uint4 v = *(const uint4*)(Wd_pack + (((size_t)(ng * 8 + nt2) * 80 + (kc * 10 + kt2)) * 64 + lane2) * 8);
    *(uint4*)&sm.wD[nt2][kt2][lane2][0] = v;
  }
  __syncthreads();

  for (int t = 0; t <= T_OUTT; t++) {
    const int pin = (t + 1) & 1, pout = t & 1;

    // ---- P1: gatesA(t) and gatesD(t-1), all 256 blocks ----
    if (t < T_OUTT)
      gatesA_ph(sm, tid, ng, kc, xs_bf + (size_t)t * 16384,
                actx_bf + pin * 32768, ah_bf, ga + (size_t)(t & 1) * 262144);
    if (t > 0)
      gatesD_ph(sm, tid, ng, kc, ah_bf, actx_bf + pin * 32768, dh_bf,
                gd + (size_t)((t - 1) & 1) * 262144);
    k++; gbar(bar, k);

    // ---- P2: lstmA [0-31] | lstmD [32-63] | conv [64-127] ----
    if (t < T_OUTT && bid < 32) {
      int b = bid * 2 + (tid >> 9);
      int jj = (tid & 511) * 2;
      float* gp = ga + (size_t)(t & 1) * 262144 + (size_t)b * 4096 + jj;
      float2 vI = ldA2(gp), vF = ldA2(gp + 1024), vG = ldA2(gp + 2048), vO = ldA2(gp + 3072);
      stA2(gp, 0.f, 0.f); stA2(gp + 1024, 0.f, 0.f);
      stA2(gp + 2048, 0.f, 0.f); stA2(gp + 3072, 0.f, 0.f);
      float2 bI = *(const float2*)(b_a + jj);
      float2 bF = *(const float2*)(b_a + 1024 + jj);
      float2 bG = *(const float2*)(b_a + 2048 + jj);
      float2 bO = *(const float2*)(b_a + 3072 + jj);
      int idx = b * 1024 + jj;
      float2 c0 = *(const float2*)(ac + idx);
      float cn0 = sigf(vF.x + bF.x) * c0.x + sigf(vI.x + bI.x) * tanhf(vG.x + bG.x);
      float cn1 = sigf(vF.y + bF.y) * c0.y + sigf(vI.y + bI.y) * tanhf(vG.y + bG.y);
      *(float2*)(ac + idx) = make_float2(cn0, cn1);
      float h0 = sigf(vO.x + bO.x) * tanhf(cn0);
      float h1 = sigf(vO.y + bO.y) * tanhf(cn1);
      stA2(ah + idx, h0, h1);
      stA4u(ah_bf + idx, packbf2(h0, h1));
    } else if (bid >= 32 && bid < 64 && t > 0) {
      int b = (bid - 32) * 2 + (tid >> 9);
      int jj = (tid & 511) * 2;
      float* gp = gd + (size_t)((t - 1) & 1) * 262144 + (size_t)b * 4096 + jj;
      float2 vI = ldA2(gp), vF = ldA2(gp + 1024), vG = ldA2(gp + 2048), vO = ldA2(gp + 3072);
      stA2(gp, 0.f, 0.f); stA2(gp + 1024, 0.f, 0.f);
      stA2(gp + 2048, 0.f, 0.f); stA2(gp + 3072, 0.f, 0.f);
      float2 bI = *(const float2*)(b_d + jj);
      float2 bF = *(const float2*)(b_d + 1024 + jj);
      float2 bG = *(const float2*)(b_d + 2048 + jj);
      float2 bO = *(const float2*)(b_d + 3072 + jj);
      int idx = b * 1024 + jj;
      float2 c0 = *(const float2*)(dc + idx);
      float cn0 = sigf(vF.x + bF.x) * c0.x + sigf(vI.x + bI.x) * tanhf(vG.x + bG.x);
      float cn1 = sigf(vF.y + bF.y) * c0.y + sigf(vI.y + bI.y) * tanhf(vG.y + bG.y);
      *(float2*)(dc + idx) = make_float2(cn0, cn1);
      float h0 = sigf(vO.x + bO.x) * tanhf(cn0);
      float h1 = sigf(vO.y + bO.y) * tanhf(cn1);
      stA2(dh + idx, h0, h1);
      stA4u(dh_bf + idx, packbf2(h0, h1));
    } else if (bid >= 64 && bid < 128 && t < T_OUTT) {
      int b = bid - 64;
      if (tid < T_INN) {
        sm.u.conv.aS[tid] = ldAf(aw + b * T_INN + tid);
        sm.u.conv.cS[tid] = ldAf(awcum + b * T_INN + tid);
      }
      for (int i = tid; i < 1984; i += 1024) sm.u.conv.wc[i] = Wconv[i];
      __syncthreads();
      int ti = tid & 255, g = tid >> 8;
      if (ti < T_INN) {
        float acc[8] = {0.f, 0.f, 0.f, 0.f, 0.f, 0.f, 0.f, 0.f};
        for (int kk = 0; kk < 31; kk++) {
          int tt = ti + kk - 15;
          if (tt >= 0 && tt < T_INN) {
            float a = sm.u.conv.aS[tt], c = sm.u.conv.cS[tt];
#pragma unroll
            for (int f = 0; f < 8; f++)
              acc[f] += sm.u.conv.wc[(g * 8 + f) * 62 + kk] * a +
                        sm.u.conv.wc[(g * 8 + f) * 62 + 31 + kk] * c;
          }
        }
#pragma unroll
        for (int f = 0; f < 8; f++)
          stAf(convG + (size_t)b * 6400 + (g * 8 + f) * T_INN + ti, acc[f]);
      }
    }
    k++; gbar(bar, k);

    // ---- P3: attention(t) [0-63] | outproj(t-1) [64-143] ----
    if (t < T_OUTT && bid < 64) {
      const int b = bid;
      sm.u.at.w.q.ahS[(tid >> 7) * 136 + (tid & 127)] = ldAf(ah + (size_t)b * 1024 + tid);
      __syncthreads();
      {
        int a = tid >> 3, kc2 = tid & 7;
        const float4* wv = (const float4*)(Wq + (size_t)a * 1024 + kc2 * 128);
        const float* hb = &sm.u.at.w.q.ahS[kc2 * 136];
        float s = 0.f;
#pragma unroll 8
        for (int i = 0; i < 32; i++) {
          float4 w4 = wv[i];
          float4 h4 = *(const float4*)(hb + i * 4);
          s += w4.x * h4.x + w4.y * h4.y + w4.z * h4.z + w4.w * h4.w;
        }
        sm.u.at.w.q.pp[tid] = s;
      }
      __syncthreads();
      if (tid < 128) {
        float s = 0.f;
#pragma unroll
        for (int j = 0; j < 8; j++) s += sm.u.at.w.q.pp[tid * 8 + j];
        sm.u.at.pq[tid] = s;
      }
      __syncthreads();
      {
        int ti = tid & 255, g = tid >> 8;
        if (ti < T_INN) {
          float cv[32];
          const float* cg = convG + (size_t)b * 6400 + ti;
#pragma unroll
          for (int f = 0; f < 32; f++) cv[f] = ldAf(cg + f * T_INN);
          const float* pm = pmT + ((size_t)b * 128 + g * 32) * T_INN + ti;
          float e = 0.f;
          for (int aa = 0; aa < 32; aa++) {
            int a = g * 32 + aa;
            float x = sm.u.at.pq[a] + pm[(size_t)aa * T_INN];
            const float* wl = Wloc + a * 32;
#pragma unroll
            for (int f = 0; f < 32; f++) x = fmaf(wl[f], cv[f], x);
            e = fmaf(vvec[a], tanhf(x), e);
          }
          sm.u.at.ep[g][ti] = e;
        }
      }
      __syncthreads();
      float ev = -3.0e38f, ex = 0.f;
      if (tid < 256) {
        if (tid < T_INN) {
          ev = sm.u.at.ep[0][tid] + sm.u.at.ep[1][tid] +
               sm.u.at.ep[2][tid] + sm.u.at.ep[3][tid];
          if (tid >= lens[b]) ev = -100000000.0f;
        }
        sm.u.at.red[tid] = ev;
      }
      __syncthreads();
      for (int s2 = 128; s2 > 0; s2 >>= 1) {
        if (tid < s2) sm.u.at.red[tid] = fmaxf(sm.u.at.red[tid], sm.u.at.red[tid + s2]);
        __syncthreads();
      }
      float mx = sm.u.at.red[0];
      __syncthreads();
      if (tid < 256) {
        ex = (tid < T_INN) ? expf(ev - mx) : 0.f;
        sm.u.at.red[tid] = ex;
      }
      __syncthreads();
      for (int s2 = 128; s2 > 0; s2 >>= 1) {
        if (tid < s2) sm.u.at.red[tid] += sm.u.at.red[tid + s2];
        __syncthreads();
      }
      float inv = 1.0f / sm.u.at.red[0];
      if (tid < 256) {
        float aval = (tid < T_INN) ? ex * inv : 0.f;
        sm.u.at.awS[tid] = aval;
        if (tid < T_INN) {
          stAf(aw + b * T_INN + tid, aval);
          stAf(awcum + b * T_INN + tid, ldAf(awcum + b * T_INN + tid) + aval);
          alignsOut[((size_t)b * T_OUTT + t) * T_INN + tid] = aval;
        }
      }
      __syncthreads();
      {
        int d = tid & 511, h = tid >> 9;
        const float* ep2 = enc + ((size_t)b * T_INN + h * 100) * DENC + d;
        float s = 0.f;
#pragma unroll 4
        for (int tt = 0; tt < 100; tt++)
          s = fmaf(sm.u.at.awS[h * 100 + tt], ep2[(size_t)tt * DENC], s);
        sm.u.at.w.q.pp[tid] = s;
      }
      __syncthreads();
      if (tid < 256) {
        int d0 = tid * 2;
        float v0 = sm.u.at.w.q.pp[d0] + sm.u.at.w.q.pp[512 + d0];
        float v1 = sm.u.at.w.q.pp[d0 + 1] + sm.u.at.w.q.pp[512 + d0 + 1];
        stA2(actx + pout * 32768 + b * DENC + d0, v0, v1);
        stA4u(actx_bf + pout * 32768 + b * DENC + d0, packbf2(v0, v1));
      }
    }
    if (t > 0 && bid >= 64 && bid < 144) {
      int ob = bid - 64;
      int oi = tid >> 4, kq = tid & 15;
      int o = ob * 64 + oi;
      int b = o / NMEL, m = o - b * NMEL;
      const float4* wp4 = (const float4*)(Wp + (size_t)m * 1536);
      const float* dhb = dh + (size_t)b * 1024;
      const float* cxb = actx + pin * 32768 + (size_t)b * 512;
      int k4 = kq * 24, k4e = k4 + 24;
      float s = 0.f;
      int ka = k4e < 256 ? k4e : 256;
      for (int i = k4; i < ka; i++) {
        float4 w4 = wp4[i];
        float2 a0 = ldA2(dhb + i * 4), a1 = ldA2(dhb + i * 4 + 2);
        s += w4.x * a0.x + w4.y * a0.y + w4.z * a1.x + w4.w * a1.y;
      }
      int kb2 = k4 > 256 ? k4 : 256;
      for (int i = kb2; i < k4e; i++) {
        float4 w4 = wp4[i];
        float2 a0 = ldA2(cxb + (i - 256) * 4), a1 = ldA2(cxb + (i - 256) * 4 + 2);
        s += w4.x * a0.x + w4.y * a0.y + w4.z * a1.x + w4.w * a1.y;
      }
      sm.u.op.red[tid] = s;
      __syncthreads();
      if (kq == 0) {
        float tot = bp[m];
#pragma unroll
        for (int j = 0; j < 16; j++) tot += sm.u.op.red[tid + j];
        outsOut[((size_t)b * T_OUTT + (t - 1)) * NMEL + m] = tot;
      }
    }
    if (t < T_OUTT) { k++; gbar(bar, k); }
  }
}

// ============================ launcher ============================
extern "C" void kernel_launch(void* const* d_in, const int* in_sizes, int n_in,
                              void* d_out, int out_size, void* d_ws, size_t ws_size,
                              hipStream_t stream)
{
  const float* enc    = (const float*)d_in[0];
  const float* dec    = (const float*)d_in[1];
  const int*   lens   = (const int*)d_in[2];
  const float* W_p1   = (const float*)d_in[3];
  const float* W_p2   = (const float*)d_in[4];
  const float* W_ih_a = (const float*)d_in[5];
  const float* W_hh_a = (const float*)d_in[6];
  const float* b_a    = (const float*)d_in[7];
  const float* Wq     = (const float*)d_in[8];
  const float* Wmem   = (const float*)d_in[9];
  const float* vvec   = (const float*)d_in[10];
  const float* Wconv  = (const float*)d_in[11];
  const float* Wloc   = (const float*)d_in[12];
  const float* W_ih_d = (const float*)d_in[13];
  const float* W_hh_d = (const float*)d_in[14];
  const float* b_d    = (const float*)d_in[15];
  const float* Wp     = (const float*)d_in[16];
  const float* bp     = (const float*)d_in[17];

  float* ws = (float*)d_ws;
  size_t off = 0;
  u16* xs_bf = (u16*)(ws + off); off += (size_t)T_OUTT * 64 * 256 / 2;
  float* pmT = ws + off; off += (size_t)64 * 128 * T_INN;
  u16* Wa_pack = (u16*)(ws + off); off += (size_t)4096 * 1792 / 2;
  u16* Wd_pack = (u16*)(ws + off); off += (size_t)4096 * 2560 / 2;
  float* stateBase = ws + off;
  float* ah    = stateBase;                       // 65536
  float* ac    = ah + 65536;
  float* dh    = ac + 65536;
  float* dc    = dh + 65536;
  float* actx  = dc + 65536;                      // 2 x 32768
  float* aw    = actx + 65536;                    // 12800
  float* awcum = aw + 12800;
  u16* ah_bf   = (u16*)(awcum + 12800);           // 65536 u16
  u16* dh_bf   = ah_bf + 65536;
  u16* actx_bf = dh_bf + 65536;                   // 2 x 32768 u16
  unsigned* bar = (unsigned*)(actx_bf + 65536);   // 1024 u32
  float* ga = (float*)(bar + 1024);               // 2 x 262144
  float* gd = ga + 524288;                        // 2 x 262144
  size_t stateFloats = (size_t)4 * 65536 + 65536 + 2 * 12800 +
                       (65536 + 65536 + 65536) / 2 + 1024 + 2 * 524288;
  off += stateFloats;
  float* convG = ws + off; off += (size_t)64 * T_INN * 32;
  float* scratch = ws + off;
  float* h1  = scratch;
  float* pmt = scratch;

  float* outsOut   = (float*)d_out;
  float* alignsOut = outsOut + (size_t)BB * T_OUTT * NMEL;

  hipMemsetAsync(stateBase, 0, stateFloats * sizeof(float), stream);
  hipMemsetAsync(xs_bf, 0, (size_t)64 * 256 * sizeof(u16), stream);

  // ---- precompute ----
  {
    int tot;
    tot = 256 * 24 * 64;
    pack_w_kernel<<<(tot + 255) / 256, 256, 0, stream>>>(W_ih_a, Wa_pack, 768, 24, 0, 56, tot);
    tot = 256 * 32 * 64;
    pack_w_kernel<<<(tot + 255) / 256, 256, 0, stream>>>(W_hh_a, Wa_pack, 1024, 32, 24, 56, tot);
    tot = 256 * 48 * 64;
    pack_w_kernel<<<(tot + 255) / 256, 256, 0, stream>>>(W_ih_d, Wd_pack, 1536, 48, 0, 80, tot);
    tot = 256 * 32 * 64;
    pack_w_kernel<<<(tot + 255) / 256, 256, 0, stream>>>(W_hh_d, Wd_pack, 1024, 32, 48, 80, tot);
  }
  gemm_pre_kernel<<<dim3(4, 399), 256, 0, stream>>>(dec, 80, W_p1, 80, h1, nullptr, 256, 80, 1);
  gemm_pre_kernel<<<dim3(4, 399), 256, 0, stream>>>(h1, 256, W_p2, 256, nullptr, xs_bf + 64 * 256, 256, 256, 1);
  gemm_pre_kernel<<<dim3(2, 200), 256, 0, stream>>>(enc, 512, Wmem, 512, pmt, nullptr, 128, 512, 0);
  transpose_pm_kernel<<<dim3(7, 4, 64), dim3(32, 8), 0, stream>>>(pmt, pmT);

  // ---- persistent weight-stationary decode loop ----
  decoder_persist<<<NBLK2, 1024, 0, stream>>>(
      enc, lens, xs_bf, pmT, Wa_pack, Wd_pack, b_a, b_d,
      Wq, Wconv, Wloc, vvec, Wp, bp,
      ah, ac, dh, dc, actx, aw, awcum, ah_bf, dh_bf, actx_bf,
      ga, gd, convG, bar, outsOut, alignsOut);
}